// Round 1
// baseline (1450.803 us; speedup 1.0000x reference)
//
#include <hip/hip_runtime.h>
#include <hip/hip_bf16.h>
#include <cmath>

#define NB 4
#define NNEG 33
#define NN 10000
#define NE 100000
#define NW 3
#define DD 64
#define NL 3
#define NR 200
#define NFL 2
#define NFFN 256
#define LN_EPS 1e-5f

// ---- ws layout (float offsets) ----
#define OFF_QUERY 0                                   // NB*DD = 256 f32
#define OFF_H0    256                                 // NB ints
#define OFF_TSW   288                                 // NB*NNEG = 132 ints
#define OFF_MINT  448                                 // 1 int
#define OFF_REL   512                                 // NL*NB*NR*DD = 153600
#define OFF_LINT  (OFF_REL + NL*NB*NR*DD)             // NL*2*DD*DD = 24576
#define OFF_WQT   (OFF_LINT + NL*2*DD*DD)             // NFL*DD*DD = 8192
#define OFF_WKT   (OFF_WQT + NFL*DD*DD)
#define OFF_WVT   (OFF_WKT + NFL*DD*DD)
#define OFF_WOT   (OFF_WVT + NFL*DD*DD)
#define OFF_F1T   (OFF_WOT + NFL*DD*DD)               // NFL*DD*NFFN = 32768
#define OFF_F2T   (OFF_F1T + NFL*DD*NFFN)             // NFL*NFFN*DD = 32768
#define OFF_M1T   (OFF_F2T + NFL*NFFN*DD)             // 2DD*2DD = 16384
#define OFF_X     (OFF_M1T + 4*DD*DD)                 // NB*NN*DD = 2560000
#define OFF_AGG   (OFF_X + NB*NN*DD)                  // NB*NN*DD
#define OFF_TOK   (OFF_AGG + NB*NN*DD)                // NB*NNEG*NW*DD = 25344

// ---------------- prep: query swap, h0, t_sw, mint init ----------------
__global__ void k_prep(const int* __restrict__ qt, const float* __restrict__ qemb,
                       float* __restrict__ ws) {
  int tid = threadIdx.x;
  if (tid < NB * DD) {
    int b = tid / DD, d = tid % DD;
    int h0 = qt[(b * NNEG + 0) * 3 + 0];
    bool itn = true;
    for (int j = 1; j < NNEG; ++j) itn = itn && (qt[(b * NNEG + j) * 3 + 0] == h0);
    int r0 = qt[(b * NNEG + 0) * 3 + 1] + (itn ? 0 : NR / 2);
    ws[OFF_QUERY + b * DD + d] = qemb[r0 * DD + d];
    if (d == 0) {
      int t0 = qt[(b * NNEG + 0) * 3 + 2];
      ((int*)ws)[OFF_H0 + b] = itn ? h0 : t0;
    }
  }
  if (tid < NB * NNEG) {
    int b = tid / NNEG, j = tid % NNEG;
    int h0 = qt[(b * NNEG + 0) * 3 + 0];
    bool itn = true;
    for (int jj = 1; jj < NNEG; ++jj) itn = itn && (qt[(b * NNEG + jj) * 3 + 0] == h0);
    int h = qt[(b * NNEG + j) * 3 + 0], t = qt[(b * NNEG + j) * 3 + 2];
    ((int*)ws)[OFF_TSW + tid] = itn ? t : h;
  }
  if (tid == 0) ((int*)ws)[OFF_MINT] = 0x7fffffff;
}

// ---------------- min over edge_time[0] ----------------
__global__ void k_mint(const int* __restrict__ etime, float* __restrict__ ws) {
  int i = blockIdx.x * blockDim.x + threadIdx.x;
  int v = (i < NE) ? etime[i] : 0x7fffffff;
  for (int m = 1; m < 64; m <<= 1) v = min(v, __shfl_xor(v, m));
  if ((threadIdx.x & 63) == 0) atomicMin(&((int*)ws)[OFF_MINT], v);
}

// ---------------- transpose weights into ws ----------------
__global__ void k_transpose(const float* __restrict__ lin_w, const float* __restrict__ wq,
                            const float* __restrict__ wk, const float* __restrict__ wv,
                            const float* __restrict__ wo, const float* __restrict__ ffw1,
                            const float* __restrict__ ffw2, const float* __restrict__ m1,
                            float* __restrict__ ws) {
  int idx = blockIdx.x * blockDim.x + threadIdx.x;
  if (idx < NL * 2 * DD * DD) {  // linT[l][k][d] = lin_w[l][d][k]
    int l = idx / (2 * DD * DD), r = idx % (2 * DD * DD), k = r / DD, d = r % DD;
    ws[OFF_LINT + idx] = lin_w[(l * DD + d) * 2 * DD + k];
    return;
  }
  idx -= NL * 2 * DD * DD;
  if (idx < 4 * NFL * DD * DD) {  // wq/wk/wv/wo T[f][k][d]
    int m = idx / (NFL * DD * DD), r2 = idx % (NFL * DD * DD);
    int f = r2 / (DD * DD), r3 = r2 % (DD * DD), k = r3 / DD, d = r3 % DD;
    const float* src = (m == 0) ? wq : (m == 1) ? wk : (m == 2) ? wv : wo;
    int off = (m == 0) ? OFF_WQT : (m == 1) ? OFF_WKT : (m == 2) ? OFF_WVT : OFF_WOT;
    ws[off + r2] = src[(f * DD + d) * DD + k];
    return;
  }
  idx -= 4 * NFL * DD * DD;
  if (idx < NFL * DD * NFFN) {  // f1T[f][k][dd] = ffw1[f][dd][k]
    int f = idx / (DD * NFFN), r2 = idx % (DD * NFFN), k = r2 / NFFN, dd = r2 % NFFN;
    ws[OFF_F1T + idx] = ffw1[(f * NFFN + dd) * DD + k];
    return;
  }
  idx -= NFL * DD * NFFN;
  if (idx < NFL * NFFN * DD) {  // f2T[f][k][d] = ffw2[f][d][k]
    int f = idx / (NFFN * DD), r2 = idx % (NFFN * DD), k = r2 / DD, d = r2 % DD;
    ws[OFF_F2T + idx] = ffw2[(f * DD + d) * NFFN + k];
    return;
  }
  idx -= NFL * NFFN * DD;
  if (idx < 2 * DD * 2 * DD) {  // m1T[k][h] = mlp_w1[h][k]
    int k = idx / (2 * DD), h = idx % (2 * DD);
    ws[OFF_M1T + idx] = m1[h * 2 * DD + k];
  }
}

// ---------------- rel[l][b][r*D+d] = query[b] @ rel_lin_w[l].T + rel_lin_b[l] ----------------
__global__ void k_rel(const float* __restrict__ rlw, const float* __restrict__ rlb,
                      float* __restrict__ ws) {
  int l = blockIdx.y;
  int rd = blockIdx.x * blockDim.x + threadIdx.x;  // < NR*DD = 12800
  const float4* wrow = (const float4*)(rlw + ((size_t)(l * NR * DD + rd)) * DD);
  float4 wreg[16];
#pragma unroll
  for (int kk = 0; kk < 16; ++kk) wreg[kk] = wrow[kk];
  float bias = rlb[l * NR * DD + rd];
  for (int b = 0; b < NB; ++b) {
    const float4* q4 = (const float4*)(ws + OFF_QUERY + b * DD);
    float acc = 0.f;
#pragma unroll
    for (int kk = 0; kk < 16; ++kk) {
      float4 q = q4[kk];
      acc += q.x * wreg[kk].x + q.y * wreg[kk].y + q.z * wreg[kk].z + q.w * wreg[kk].w;
    }
    ws[OFF_REL + (l * NB + b) * NR * DD + rd] = acc + bias;
  }
}

// ---------------- fill buf with init pattern (zeros + query at h0) ----------------
__global__ void k_fill_init(float* __restrict__ buf, const float* __restrict__ ws) {
  int i = blockIdx.x * 256 + threadIdx.x;  // < NB*NN*DD
  int b = i / (NN * DD);
  int r = i % (NN * DD);
  int n = r / DD, d = r % DD;
  int h0 = ((const int*)ws)[OFF_H0 + b];
  buf[i] = (n == h0) ? ws[OFF_QUERY + b * DD + d] : 0.f;
}

// ---------------- edge messages + scatter ----------------
__global__ void k_msg(const int* __restrict__ eidx, const int* __restrict__ etype,
                      const int* __restrict__ etime, const float* __restrict__ eweight,
                      const float* __restrict__ tw, const float* __restrict__ tb,
                      float* __restrict__ ws, int w, int l) {
  int wv = threadIdx.x >> 6, d = threadIdx.x & 63;
  int e = blockIdx.x * 4 + wv;
  int b = blockIdx.y;
  int src = eidx[(w * 2 + 0) * NE + e];
  int dst = eidx[(w * 2 + 1) * NE + e];
  int et = etype[w * NE + e];
  float dt = (float)etime[w * NE + e] - (float)((const int*)ws)[OFF_MINT];
  float twv = tw[(l * NR + et) * DD + d];
  float tbv = tb[(l * NR + et) * DD + d];
  float te = cosf(dt * twv + tbv);
  float xv = ws[OFF_X + (b * NN + src) * DD + d];
  float rv = ws[OFF_REL + ((l * NB + b) * NR + et) * DD + d];
  float wgt = eweight[w * NE + e];
  atomicAdd(ws + OFF_AGG + (b * NN + dst) * DD + d, xv * rv * te * wgt);
}

// ---------------- node update: hid = [x,agg]@linT + b; x += relu(LN(hid)) ----------------
__global__ void k_node(const float* __restrict__ linb, const float* __restrict__ lns,
                       const float* __restrict__ lnb, float* __restrict__ ws, int l) {
  __shared__ float rowbuf[4][2 * DD];
  int wv = threadIdx.x >> 6, d = threadIdx.x & 63;
  int n = blockIdx.x * 4 + wv, b = blockIdx.y;
  int base = (b * NN + n) * DD + d;
  float xv = ws[OFF_X + base];
  float av = ws[OFF_AGG + base];
  rowbuf[wv][d] = xv;
  rowbuf[wv][DD + d] = av;
  __syncthreads();
  float acc = linb[l * DD + d];
  const float* WT = ws + OFF_LINT + l * 2 * DD * DD;
#pragma unroll 8
  for (int k = 0; k < 2 * DD; ++k) acc += rowbuf[wv][k] * WT[k * DD + d];
  // LayerNorm over 64 lanes
  float s = acc;
  for (int m = 1; m < 64; m <<= 1) s += __shfl_xor(s, m);
  float mean = s * (1.f / 64.f);
  float c = acc - mean;
  float v = c * c;
  for (int m = 1; m < 64; m <<= 1) v += __shfl_xor(v, m);
  v *= (1.f / 64.f);
  float y = c / sqrtf(v + LN_EPS) * lns[l * DD + d] + lnb[l * DD + d];
  y = fmaxf(y, 0.f);
  ws[OFF_X + base] = xv + y;
}

// ---------------- gather tail features into tokens (+pe) ----------------
__global__ void k_gather(const float* __restrict__ pe, float* __restrict__ ws, int w) {
  int i = blockIdx.x * 256 + threadIdx.x;  // < NB*NNEG*DD = 8448
  if (i >= NB * NNEG * DD) return;
  int bj = i / DD, d = i % DD;
  int b = bj / NNEG;
  int t = ((const int*)ws)[OFF_TSW + bj];
  ws[OFF_TOK + bj * NW * DD + w * DD + d] =
      ws[OFF_X + (b * NN + t) * DD + d] + pe[w * DD + d];
}

// ---------------- transformer (2 layers) + final MLP, one block per (b,neg) row ----------------
__global__ void k_xform(const float* __restrict__ ffb1, const float* __restrict__ ffb2,
                        const float* __restrict__ fln1s, const float* __restrict__ fln1b,
                        const float* __restrict__ fln2s, const float* __restrict__ fln2b,
                        const float* __restrict__ m1b, const float* __restrict__ m2w,
                        const float* __restrict__ m2b, float* __restrict__ ws,
                        float* __restrict__ out) {
  __shared__ float tok[NW][DD], kb[NW][DD], vb[NW][DD], hb[NW][NFFN], feat[2 * DD];
  int tk = threadIdx.x / 64, d = threadIdx.x % 64;
  int row = blockIdx.x, b = row / NNEG;
  tok[tk][d] = ws[OFF_TOK + row * NW * DD + tk * DD + d];
  __syncthreads();
  for (int f = 0; f < NFL; ++f) {
    const float* WQ = ws + OFF_WQT + f * DD * DD;
    const float* WK = ws + OFF_WKT + f * DD * DD;
    const float* WV = ws + OFF_WVT + f * DD * DD;
    float qd = 0.f, kd = 0.f, vd = 0.f;
    for (int k = 0; k < DD; ++k) {
      float tv = tok[tk][k];
      qd += tv * WQ[k * DD + d];
      kd += tv * WK[k * DD + d];
      vd += tv * WV[k * DD + d];
    }
    kb[tk][d] = kd;
    vb[tk][d] = vd;
    __syncthreads();
    // attention scores per head (head = d>>4), keys j=0..2
    float sc[NW];
    for (int j = 0; j < NW; ++j) {
      float p = qd * kb[j][d];
      p += __shfl_xor(p, 1);
      p += __shfl_xor(p, 2);
      p += __shfl_xor(p, 4);
      p += __shfl_xor(p, 8);
      sc[j] = p * 0.25f;  // 1/sqrt(16)
    }
    float mx = fmaxf(sc[0], fmaxf(sc[1], sc[2]));
    float e0 = expf(sc[0] - mx), e1 = expf(sc[1] - mx), e2 = expf(sc[2] - mx);
    float inv = 1.f / (e0 + e1 + e2);
    float od = (e0 * vb[0][d] + e1 * vb[1][d] + e2 * vb[2][d]) * inv;
    // o @ wo.T  (ob is wave-private: reuse feat? use kb after sync barrier below)
    __syncthreads();
    kb[tk][d] = od;  // reuse kb as o-buffer (all waves synced above)
    float ao = 0.f;
    const float* WO = ws + OFF_WOT + f * DD * DD;
    for (int k = 0; k < DD; ++k) ao += kb[tk][k] * WO[k * DD + d];
    float t1 = tok[tk][d] + ao;
    // LN1
    float s = t1;
    for (int m = 1; m < 64; m <<= 1) s += __shfl_xor(s, m);
    float mean = s / 64.f;
    float c = t1 - mean;
    float v = c * c;
    for (int m = 1; m < 64; m <<= 1) v += __shfl_xor(v, m);
    v /= 64.f;
    t1 = c / sqrtf(v + LN_EPS) * fln1s[f * DD + d] + fln1b[f * DD + d];
    tok[tk][d] = t1;  // wave-private row
    // FFN
    const float* F1 = ws + OFF_F1T + f * DD * NFFN;
    float h[4];
#pragma unroll
    for (int u = 0; u < 4; ++u) h[u] = ffb1[f * NFFN + d + 64 * u];
    for (int k = 0; k < DD; ++k) {
      float tv = tok[tk][k];
#pragma unroll
      for (int u = 0; u < 4; ++u) h[u] += tv * F1[k * NFFN + d + 64 * u];
    }
#pragma unroll
    for (int u = 0; u < 4; ++u) hb[tk][d + 64 * u] = fmaxf(h[u], 0.f);
    const float* F2 = ws + OFF_F2T + f * NFFN * DD;
    float ff = ffb2[f * DD + d];
    for (int k = 0; k < NFFN; ++k) ff += hb[tk][k] * F2[k * DD + d];
    float t2 = t1 + ff;
    s = t2;
    for (int m = 1; m < 64; m <<= 1) s += __shfl_xor(s, m);
    mean = s / 64.f;
    c = t2 - mean;
    v = c * c;
    for (int m = 1; m < 64; m <<= 1) v += __shfl_xor(v, m);
    v /= 64.f;
    t2 = c / sqrtf(v + LN_EPS) * fln2s[f * DD + d] + fln2b[f * DD + d];
    tok[tk][d] = t2;
    __syncthreads();
  }
  // final MLP on last token
  if (tk == 2) {
    feat[d] = tok[2][d];
    feat[DD + d] = ws[OFF_QUERY + b * DD + d];
  }
  __syncthreads();
  if (tk == 0) {
    const float* M1 = ws + OFF_M1T;
    float h0 = m1b[d], h1 = m1b[DD + d];
    for (int k = 0; k < 2 * DD; ++k) {
      float fv = feat[k];
      h0 += fv * M1[k * 2 * DD + d];
      h1 += fv * M1[k * 2 * DD + DD + d];
    }
    h0 = fmaxf(h0, 0.f);
    h1 = fmaxf(h1, 0.f);
    float part = h0 * m2w[d] + h1 * m2w[DD + d];
    for (int m = 1; m < 64; m <<= 1) part += __shfl_xor(part, m);
    if (d == 0) out[row] = part + m2b[0];
  }
}

extern "C" void kernel_launch(void* const* d_in, const int* in_sizes, int n_in,
                              void* d_out, int out_size, void* d_ws, size_t ws_size,
                              hipStream_t stream) {
  const int* qt = (const int*)d_in[0];
  const int* eidx = (const int*)d_in[1];
  const int* etype = (const int*)d_in[2];
  const int* etime = (const int*)d_in[3];
  const float* qemb = (const float*)d_in[4];
  const float* ew = (const float*)d_in[5];
  const float* rlw = (const float*)d_in[6];
  const float* rlb = (const float*)d_in[7];
  const float* tw = (const float*)d_in[8];
  const float* tb = (const float*)d_in[9];
  const float* linw = (const float*)d_in[10];
  const float* linb = (const float*)d_in[11];
  const float* lns = (const float*)d_in[12];
  const float* lnb = (const float*)d_in[13];
  const float* pe = (const float*)d_in[14];
  const float* wq = (const float*)d_in[15];
  const float* wk = (const float*)d_in[16];
  const float* wv = (const float*)d_in[17];
  const float* wo = (const float*)d_in[18];
  const float* ffw1 = (const float*)d_in[19];
  const float* ffb1 = (const float*)d_in[20];
  const float* ffw2 = (const float*)d_in[21];
  const float* ffb2 = (const float*)d_in[22];
  const float* fln1s = (const float*)d_in[23];
  const float* fln1b = (const float*)d_in[24];
  const float* fln2s = (const float*)d_in[25];
  const float* fln2b = (const float*)d_in[26];
  const float* m1w = (const float*)d_in[27];
  const float* m1b = (const float*)d_in[28];
  const float* m2w = (const float*)d_in[29];
  const float* m2b = (const float*)d_in[30];
  float* ws = (float*)d_ws;
  float* out = (float*)d_out;

  k_prep<<<1, 256, 0, stream>>>(qt, qemb, ws);
  k_mint<<<(NE + 255) / 256, 256, 0, stream>>>(etime, ws);
  {
    int total = NL * 2 * DD * DD + 4 * NFL * DD * DD + NFL * DD * NFFN + NFL * NFFN * DD +
                2 * DD * 2 * DD;
    k_transpose<<<(total + 255) / 256, 256, 0, stream>>>(linw, wq, wk, wv, wo, ffw1, ffw2,
                                                          m1w, ws);
  }
  k_rel<<<dim3(NR * DD / 256, NL), 256, 0, stream>>>(rlw, rlb, ws);

  for (int w = 0; w < NW; ++w) {
    k_fill_init<<<NB * NN * DD / 256, 256, 0, stream>>>(ws + OFF_X, ws);
    for (int l = 0; l < NL; ++l) {
      k_fill_init<<<NB * NN * DD / 256, 256, 0, stream>>>(ws + OFF_AGG, ws);
      k_msg<<<dim3(NE / 4, NB), 256, 0, stream>>>(eidx, etype, etime, ew, tw, tb, ws, w, l);
      k_node<<<dim3(NN / 4, NB), 256, 0, stream>>>(linb, lns, lnb, ws, l);
    }
    k_gather<<<(NB * NNEG * DD + 255) / 256, 256, 0, stream>>>(pe, ws, w);
  }
  k_xform<<<NB * NNEG, 192, 0, stream>>>(ffb1, ffb2, fln1s, fln1b, fln2s, fln2b, m1b, m2w,
                                          m2b, ws, out);
}

// Round 2
// 689.328 us; speedup vs baseline: 2.1047x; 2.1047x over previous
//
#include <hip/hip_runtime.h>
#include <hip/hip_bf16.h>
#include <cmath>

#define NB 4
#define NNEG 33
#define NN 10000
#define NE 100000
#define NW 3
#define DD 64
#define NL 3
#define NR 200
#define NFL 2
#define NFFN 256
#define LN_EPS 1e-5f

// ---- ws layout (float offsets) ----
#define OFF_QUERY 0                                   // NB*DD
#define OFF_H0    256                                 // NB ints
#define OFF_TSW   288                                 // NB*NNEG ints
#define OFF_MINT  448                                 // 1 int
#define OFF_REL   512                                 // NL*NB*NR*DD
#define OFF_LINT  (OFF_REL + NL*NB*NR*DD)             // NL*2*DD*DD
#define OFF_WQT   (OFF_LINT + NL*2*DD*DD)
#define OFF_WKT   (OFF_WQT + NFL*DD*DD)
#define OFF_WVT   (OFF_WKT + NFL*DD*DD)
#define OFF_WOT   (OFF_WVT + NFL*DD*DD)
#define OFF_F1T   (OFF_WOT + NFL*DD*DD)
#define OFF_F2T   (OFF_F1T + NFL*DD*NFFN)
#define OFF_M1T   (OFF_F2T + NFL*NFFN*DD)
#define OFF_X     (OFF_M1T + 4*DD*DD)                 // NB*NN*DD
#define OFF_AGG   (OFF_X + NB*NN*DD)                  // NB*NN*DD
#define OFF_TOK   (OFF_AGG + NB*NN*DD)                // NB*NNEG*NW*DD
#define OFF_X2    (OFF_TOK + NB*NNEG*NW*DD)           // NB*NN*DD
// int offsets (4B units, same scale as float offsets)
#define IOFF_PTR  (OFF_X2 + NB*NN*DD)                 // NW*(NN+1) ints
#define IOFF_CUR  (IOFF_PTR + NW*(NN+1))              // NW*NN ints
#define IOFF_REC  ((IOFF_CUR + NW*NN + 3) & ~3)       // NW*NE*4 ints, 16B aligned

// ---------------- prep ----------------
__global__ void k_prep(const int* __restrict__ qt, const float* __restrict__ qemb,
                       float* __restrict__ ws) {
  int tid = threadIdx.x;
  if (tid < NB * DD) {
    int b = tid / DD, d = tid % DD;
    int h0 = qt[(b * NNEG + 0) * 3 + 0];
    bool itn = true;
    for (int j = 1; j < NNEG; ++j) itn = itn && (qt[(b * NNEG + j) * 3 + 0] == h0);
    int r0 = qt[(b * NNEG + 0) * 3 + 1] + (itn ? 0 : NR / 2);
    ws[OFF_QUERY + b * DD + d] = qemb[r0 * DD + d];
    if (d == 0) {
      int t0 = qt[(b * NNEG + 0) * 3 + 2];
      ((int*)ws)[OFF_H0 + b] = itn ? h0 : t0;
    }
  }
  if (tid < NB * NNEG) {
    int b = tid / NNEG, j = tid % NNEG;
    int h0 = qt[(b * NNEG + 0) * 3 + 0];
    bool itn = true;
    for (int jj = 1; jj < NNEG; ++jj) itn = itn && (qt[(b * NNEG + jj) * 3 + 0] == h0);
    int h = qt[(b * NNEG + j) * 3 + 0], t = qt[(b * NNEG + j) * 3 + 2];
    ((int*)ws)[OFF_TSW + tid] = itn ? t : h;
  }
  if (tid == 0) ((int*)ws)[OFF_MINT] = 0x7fffffff;
}

// ---------------- min over edge_time[0] ----------------
__global__ void k_mint(const int* __restrict__ etime, float* __restrict__ ws) {
  int i = blockIdx.x * blockDim.x + threadIdx.x;
  int v = (i < NE) ? etime[i] : 0x7fffffff;
  for (int m = 1; m < 64; m <<= 1) v = min(v, __shfl_xor(v, m));
  if ((threadIdx.x & 63) == 0) atomicMin(&((int*)ws)[OFF_MINT], v);
}

// ---------------- zero ptr array ----------------
__global__ void k_zero_ptr(float* __restrict__ ws) {
  int i = blockIdx.x * 256 + threadIdx.x;
  if (i < NW * (NN + 1)) ((int*)ws)[IOFF_PTR + i] = 0;
}

// ---------------- histogram of dst ----------------
__global__ void k_hist(const int* __restrict__ eidx, float* __restrict__ ws) {
  int e = blockIdx.x * 256 + threadIdx.x, w = blockIdx.y;
  if (e >= NE) return;
  int dst = eidx[(w * 2 + 1) * NE + e];
  atomicAdd(&((int*)ws)[IOFF_PTR + w * (NN + 1) + dst + 1], 1);
}

// ---------------- inclusive scan -> ptr (one block per w) ----------------
__global__ void k_scan(float* __restrict__ ws) {
  int w = blockIdx.x;
  int* p = (int*)ws + IOFF_PTR + w * (NN + 1);
  __shared__ int wsum[4];
  __shared__ int runv;
  if (threadIdx.x == 0) runv = 0;
  __syncthreads();
  int lane = threadIdx.x & 63, wv = threadIdx.x >> 6;
  for (int base = 0; base < NN + 1; base += 256) {
    int i = base + threadIdx.x;
    int v = (i <= NN) ? p[i] : 0;
    for (int off = 1; off < 64; off <<= 1) {
      int t = __shfl_up(v, off);
      if (lane >= off) v += t;
    }
    if (lane == 63) wsum[wv] = v;
    __syncthreads();
    int add = runv;
    for (int u = 0; u < wv; ++u) add += wsum[u];
    v += add;
    if (i <= NN) p[i] = v;
    __syncthreads();
    if (threadIdx.x == 255) runv = v;
    __syncthreads();
  }
}

// ---------------- cursor init ----------------
__global__ void k_curinit(float* __restrict__ ws) {
  int i = blockIdx.x * 256 + threadIdx.x;
  if (i >= NW * NN) return;
  int w = i / NN, n = i % NN;
  ((int*)ws)[IOFF_CUR + i] = ((int*)ws)[IOFF_PTR + w * (NN + 1) + n];
}

// ---------------- scatter edges into CSR records {src, et, dt, weight} ----------------
__global__ void k_scatter(const int* __restrict__ eidx, const int* __restrict__ etype,
                          const int* __restrict__ etime, const float* __restrict__ eweight,
                          float* __restrict__ ws) {
  int e = blockIdx.x * 256 + threadIdx.x, w = blockIdx.y;
  if (e >= NE) return;
  int* wsi = (int*)ws;
  int dst = eidx[(w * 2 + 1) * NE + e];
  int pos = atomicAdd(&wsi[IOFF_CUR + w * NN + dst], 1);
  float dt = (float)etime[w * NE + e] - (float)wsi[OFF_MINT];
  int4 rec;
  rec.x = eidx[(w * 2 + 0) * NE + e];
  rec.y = etype[w * NE + e];
  rec.z = __float_as_int(dt);
  rec.w = __float_as_int(eweight[w * NE + e]);
  ((int4*)(wsi + IOFF_REC))[(size_t)w * NE + pos] = rec;
}

// ---------------- transpose weights ----------------
__global__ void k_transpose(const float* __restrict__ lin_w, const float* __restrict__ wq,
                            const float* __restrict__ wk, const float* __restrict__ wv,
                            const float* __restrict__ wo, const float* __restrict__ ffw1,
                            const float* __restrict__ ffw2, const float* __restrict__ m1,
                            float* __restrict__ ws) {
  int idx = blockIdx.x * blockDim.x + threadIdx.x;
  if (idx < NL * 2 * DD * DD) {
    int l = idx / (2 * DD * DD), r = idx % (2 * DD * DD), k = r / DD, d = r % DD;
    ws[OFF_LINT + idx] = lin_w[(l * DD + d) * 2 * DD + k];
    return;
  }
  idx -= NL * 2 * DD * DD;
  if (idx < 4 * NFL * DD * DD) {
    int m = idx / (NFL * DD * DD), r2 = idx % (NFL * DD * DD);
    int f = r2 / (DD * DD), r3 = r2 % (DD * DD), k = r3 / DD, d = r3 % DD;
    const float* src = (m == 0) ? wq : (m == 1) ? wk : (m == 2) ? wv : wo;
    int off = (m == 0) ? OFF_WQT : (m == 1) ? OFF_WKT : (m == 2) ? OFF_WVT : OFF_WOT;
    ws[off + r2] = src[(f * DD + d) * DD + k];
    return;
  }
  idx -= 4 * NFL * DD * DD;
  if (idx < NFL * DD * NFFN) {
    int f = idx / (DD * NFFN), r2 = idx % (DD * NFFN), k = r2 / NFFN, dd = r2 % NFFN;
    ws[OFF_F1T + idx] = ffw1[(f * NFFN + dd) * DD + k];
    return;
  }
  idx -= NFL * DD * NFFN;
  if (idx < NFL * NFFN * DD) {
    int f = idx / (NFFN * DD), r2 = idx % (NFFN * DD), k = r2 / DD, d = r2 % DD;
    ws[OFF_F2T + idx] = ffw2[(f * DD + d) * NFFN + k];
    return;
  }
  idx -= NFL * NFFN * DD;
  if (idx < 2 * DD * 2 * DD) {
    int k = idx / (2 * DD), h = idx % (2 * DD);
    ws[OFF_M1T + idx] = m1[h * 2 * DD + k];
  }
}

// ---------------- rel = query @ rel_lin_w.T + b ----------------
__global__ void k_rel(const float* __restrict__ rlw, const float* __restrict__ rlb,
                      float* __restrict__ ws) {
  int l = blockIdx.y;
  int rd = blockIdx.x * blockDim.x + threadIdx.x;
  const float4* wrow = (const float4*)(rlw + ((size_t)(l * NR * DD + rd)) * DD);
  float4 wreg[16];
#pragma unroll
  for (int kk = 0; kk < 16; ++kk) wreg[kk] = wrow[kk];
  float bias = rlb[l * NR * DD + rd];
  for (int b = 0; b < NB; ++b) {
    const float4* q4 = (const float4*)(ws + OFF_QUERY + b * DD);
    float acc = 0.f;
#pragma unroll
    for (int kk = 0; kk < 16; ++kk) {
      float4 q = q4[kk];
      acc += q.x * wreg[kk].x + q.y * wreg[kk].y + q.z * wreg[kk].z + q.w * wreg[kk].w;
    }
    ws[OFF_REL + (l * NB + b) * NR * DD + rd] = acc + bias;
  }
}

// ---------------- fill buf with init pattern ----------------
__global__ void k_fill_init(float* __restrict__ buf, const float* __restrict__ ws) {
  int i = blockIdx.x * 256 + threadIdx.x;
  int b = i / (NN * DD);
  int r = i % (NN * DD);
  int n = r / DD, d = r % DD;
  int h0 = ((const int*)ws)[OFF_H0 + b];
  buf[i] = (n == h0) ? ws[OFF_QUERY + b * DD + d] : 0.f;
}

// ---------------- CSR gather aggregation: wave per node, 4 batches inside ----------------
__global__ __launch_bounds__(256) void k_agg(const float* __restrict__ tw,
                                             const float* __restrict__ tb,
                                             const float* __restrict__ xcur,
                                             float* __restrict__ ws, int w, int l) {
  int wv = threadIdx.x >> 6, d = threadIdx.x & 63;
  int n = blockIdx.x * 4 + wv;
  const int* wsi = (const int*)ws;
  int p0 = wsi[IOFF_PTR + w * (NN + 1) + n];
  int p1 = wsi[IOFF_PTR + w * (NN + 1) + n + 1];
  const int4* recs = ((const int4*)(wsi + IOFF_REC)) + (size_t)w * NE;
  const float* twl = tw + l * NR * DD;
  const float* tbl = tb + l * NR * DD;
  const float* rell = ws + OFF_REL + l * NB * NR * DD;
  float a0 = (n == wsi[OFF_H0 + 0]) ? ws[OFF_QUERY + 0 * DD + d] : 0.f;
  float a1 = (n == wsi[OFF_H0 + 1]) ? ws[OFF_QUERY + 1 * DD + d] : 0.f;
  float a2 = (n == wsi[OFF_H0 + 2]) ? ws[OFF_QUERY + 2 * DD + d] : 0.f;
  float a3 = (n == wsi[OFF_H0 + 3]) ? ws[OFF_QUERY + 3 * DD + d] : 0.f;
  for (int j = p0; j < p1; ++j) {
    int4 rec = recs[j];
    int src = rec.x, et = rec.y;
    float dt = __int_as_float(rec.z), wgt = __int_as_float(rec.w);
    float te = cosf(fmaf(dt, twl[et * DD + d], tbl[et * DD + d])) * wgt;
    const float* xb = xcur + src * DD + d;
    const float* rb = rell + et * DD + d;
    a0 = fmaf(xb[0 * NN * DD] * rb[0 * NR * DD], te, a0);
    a1 = fmaf(xb[1 * NN * DD] * rb[1 * NR * DD], te, a1);
    a2 = fmaf(xb[2 * NN * DD] * rb[2 * NR * DD], te, a2);
    a3 = fmaf(xb[3 * NN * DD] * rb[3 * NR * DD], te, a3);
  }
  float* agg = ws + OFF_AGG;
  agg[(0 * NN + n) * DD + d] = a0;
  agg[(1 * NN + n) * DD + d] = a1;
  agg[(2 * NN + n) * DD + d] = a2;
  agg[(3 * NN + n) * DD + d] = a3;
}

// ---------------- node GEMM + LN + residual; wave = 8 rows x 64 cols ----------------
__global__ __launch_bounds__(256) void k_gemm(const float* __restrict__ linb,
                                              const float* __restrict__ lns,
                                              const float* __restrict__ lnb,
                                              const float* __restrict__ xsrc,
                                              float* __restrict__ xdst,
                                              const float* __restrict__ ws, int l) {
  int wv = __builtin_amdgcn_readfirstlane(threadIdx.x >> 6);
  int c = threadIdx.x & 63;
  int row0 = blockIdx.x * 32 + wv * 8;
  const float* WT = ws + OFF_LINT + l * 2 * DD * DD;  // [128][64]
  const float* aggsrc = ws + OFF_AGG;
  float bias = linb[l * DD + c];
  float acc[8];
#pragma unroll
  for (int r = 0; r < 8; ++r) acc[r] = bias;
  // x part (k = 0..63)
  for (int kk = 0; kk < 16; ++kk) {
    float w0 = WT[(4 * kk + 0) * DD + c];
    float w1 = WT[(4 * kk + 1) * DD + c];
    float w2 = WT[(4 * kk + 2) * DD + c];
    float w3 = WT[(4 * kk + 3) * DD + c];
#pragma unroll
    for (int r = 0; r < 8; ++r) {
      float4 xv = *(const float4*)(xsrc + (size_t)(row0 + r) * DD + 4 * kk);
      acc[r] = fmaf(xv.x, w0, acc[r]);
      acc[r] = fmaf(xv.y, w1, acc[r]);
      acc[r] = fmaf(xv.z, w2, acc[r]);
      acc[r] = fmaf(xv.w, w3, acc[r]);
    }
  }
  // agg part (k = 64..127)
  for (int kk = 0; kk < 16; ++kk) {
    float w0 = WT[(64 + 4 * kk + 0) * DD + c];
    float w1 = WT[(64 + 4 * kk + 1) * DD + c];
    float w2 = WT[(64 + 4 * kk + 2) * DD + c];
    float w3 = WT[(64 + 4 * kk + 3) * DD + c];
#pragma unroll
    for (int r = 0; r < 8; ++r) {
      float4 xv = *(const float4*)(aggsrc + (size_t)(row0 + r) * DD + 4 * kk);
      acc[r] = fmaf(xv.x, w0, acc[r]);
      acc[r] = fmaf(xv.y, w1, acc[r]);
      acc[r] = fmaf(xv.z, w2, acc[r]);
      acc[r] = fmaf(xv.w, w3, acc[r]);
    }
  }
  float sc = lns[l * DD + c], bc = lnb[l * DD + c];
#pragma unroll
  for (int r = 0; r < 8; ++r) {
    float v = acc[r];
    float s = v;
    for (int m = 1; m < 64; m <<= 1) s += __shfl_xor(s, m);
    float mean = s * (1.f / 64.f);
    float cv = v - mean;
    float vv = cv * cv;
    for (int m = 1; m < 64; m <<= 1) vv += __shfl_xor(vv, m);
    vv *= (1.f / 64.f);
    float y = cv * __frsqrt_rn(vv + LN_EPS) * sc + bc;
    y = fmaxf(y, 0.f);
    float xo = xsrc[(size_t)(row0 + r) * DD + c];
    xdst[(size_t)(row0 + r) * DD + c] = xo + y;
  }
}

// ---------------- gather tail features into tokens (+pe) ----------------
__global__ void k_gather(const float* __restrict__ pe, const float* __restrict__ xfin,
                         float* __restrict__ ws, int w) {
  int i = blockIdx.x * 256 + threadIdx.x;
  if (i >= NB * NNEG * DD) return;
  int bj = i / DD, d = i % DD;
  int b = bj / NNEG;
  int t = ((const int*)ws)[OFF_TSW + bj];
  ws[OFF_TOK + bj * NW * DD + w * DD + d] = xfin[(b * NN + t) * DD + d] + pe[w * DD + d];
}

// ---------------- transformer + final MLP ----------------
__global__ void k_xform(const float* __restrict__ ffb1, const float* __restrict__ ffb2,
                        const float* __restrict__ fln1s, const float* __restrict__ fln1b,
                        const float* __restrict__ fln2s, const float* __restrict__ fln2b,
                        const float* __restrict__ m1b, const float* __restrict__ m2w,
                        const float* __restrict__ m2b, float* __restrict__ ws,
                        float* __restrict__ out) {
  __shared__ float tok[NW][DD], kb[NW][DD], vb[NW][DD], hb[NW][NFFN], feat[2 * DD];
  int tk = threadIdx.x / 64, d = threadIdx.x % 64;
  int row = blockIdx.x, b = row / NNEG;
  tok[tk][d] = ws[OFF_TOK + row * NW * DD + tk * DD + d];
  __syncthreads();
  for (int f = 0; f < NFL; ++f) {
    const float* WQ = ws + OFF_WQT + f * DD * DD;
    const float* WK = ws + OFF_WKT + f * DD * DD;
    const float* WV = ws + OFF_WVT + f * DD * DD;
    float qd = 0.f, kd = 0.f, vd = 0.f;
    for (int k = 0; k < DD; ++k) {
      float tv = tok[tk][k];
      qd += tv * WQ[k * DD + d];
      kd += tv * WK[k * DD + d];
      vd += tv * WV[k * DD + d];
    }
    kb[tk][d] = kd;
    vb[tk][d] = vd;
    __syncthreads();
    float sc[NW];
    for (int j = 0; j < NW; ++j) {
      float p = qd * kb[j][d];
      p += __shfl_xor(p, 1);
      p += __shfl_xor(p, 2);
      p += __shfl_xor(p, 4);
      p += __shfl_xor(p, 8);
      sc[j] = p * 0.25f;
    }
    float mx = fmaxf(sc[0], fmaxf(sc[1], sc[2]));
    float e0 = expf(sc[0] - mx), e1 = expf(sc[1] - mx), e2 = expf(sc[2] - mx);
    float inv = 1.f / (e0 + e1 + e2);
    float od = (e0 * vb[0][d] + e1 * vb[1][d] + e2 * vb[2][d]) * inv;
    __syncthreads();
    kb[tk][d] = od;
    float ao = 0.f;
    const float* WO = ws + OFF_WOT + f * DD * DD;
    for (int k = 0; k < DD; ++k) ao += kb[tk][k] * WO[k * DD + d];
    float t1 = tok[tk][d] + ao;
    float s = t1;
    for (int m = 1; m < 64; m <<= 1) s += __shfl_xor(s, m);
    float mean = s / 64.f;
    float cv = t1 - mean;
    float v = cv * cv;
    for (int m = 1; m < 64; m <<= 1) v += __shfl_xor(v, m);
    v /= 64.f;
    t1 = cv / sqrtf(v + LN_EPS) * fln1s[f * DD + d] + fln1b[f * DD + d];
    tok[tk][d] = t1;
    const float* F1 = ws + OFF_F1T + f * DD * NFFN;
    float h[4];
#pragma unroll
    for (int u = 0; u < 4; ++u) h[u] = ffb1[f * NFFN + d + 64 * u];
    for (int k = 0; k < DD; ++k) {
      float tv = tok[tk][k];
#pragma unroll
      for (int u = 0; u < 4; ++u) h[u] += tv * F1[k * NFFN + d + 64 * u];
    }
#pragma unroll
    for (int u = 0; u < 4; ++u) hb[tk][d + 64 * u] = fmaxf(h[u], 0.f);
    const float* F2 = ws + OFF_F2T + f * NFFN * DD;
    float ff = ffb2[f * DD + d];
    for (int k = 0; k < NFFN; ++k) ff += hb[tk][k] * F2[k * DD + d];
    float t2 = t1 + ff;
    s = t2;
    for (int m = 1; m < 64; m <<= 1) s += __shfl_xor(s, m);
    mean = s / 64.f;
    cv = t2 - mean;
    v = cv * cv;
    for (int m = 1; m < 64; m <<= 1) v += __shfl_xor(v, m);
    v /= 64.f;
    t2 = cv / sqrtf(v + LN_EPS) * fln2s[f * DD + d] + fln2b[f * DD + d];
    tok[tk][d] = t2;
    __syncthreads();
  }
  if (tk == 2) {
    feat[d] = tok[2][d];
    feat[DD + d] = ws[OFF_QUERY + b * DD + d];
  }
  __syncthreads();
  if (tk == 0) {
    const float* M1 = ws + OFF_M1T;
    float h0 = m1b[d], h1 = m1b[DD + d];
    for (int k = 0; k < 2 * DD; ++k) {
      float fv = feat[k];
      h0 += fv * M1[k * 2 * DD + d];
      h1 += fv * M1[k * 2 * DD + DD + d];
    }
    h0 = fmaxf(h0, 0.f);
    h1 = fmaxf(h1, 0.f);
    float part = h0 * m2w[d] + h1 * m2w[DD + d];
    for (int m = 1; m < 64; m <<= 1) part += __shfl_xor(part, m);
    if (d == 0) out[row] = part + m2b[0];
  }
}

extern "C" void kernel_launch(void* const* d_in, const int* in_sizes, int n_in,
                              void* d_out, int out_size, void* d_ws, size_t ws_size,
                              hipStream_t stream) {
  const int* qt = (const int*)d_in[0];
  const int* eidx = (const int*)d_in[1];
  const int* etype = (const int*)d_in[2];
  const int* etime = (const int*)d_in[3];
  const float* qemb = (const float*)d_in[4];
  const float* ew = (const float*)d_in[5];
  const float* rlw = (const float*)d_in[6];
  const float* rlb = (const float*)d_in[7];
  const float* tw = (const float*)d_in[8];
  const float* tb = (const float*)d_in[9];
  const float* linw = (const float*)d_in[10];
  const float* linb = (const float*)d_in[11];
  const float* lns = (const float*)d_in[12];
  const float* lnb = (const float*)d_in[13];
  const float* pe = (const float*)d_in[14];
  const float* wq = (const float*)d_in[15];
  const float* wk = (const float*)d_in[16];
  const float* wv = (const float*)d_in[17];
  const float* wo = (const float*)d_in[18];
  const float* ffw1 = (const float*)d_in[19];
  const float* ffb1 = (const float*)d_in[20];
  const float* ffw2 = (const float*)d_in[21];
  const float* ffb2 = (const float*)d_in[22];
  const float* fln1s = (const float*)d_in[23];
  const float* fln1b = (const float*)d_in[24];
  const float* fln2s = (const float*)d_in[25];
  const float* fln2b = (const float*)d_in[26];
  const float* m1w = (const float*)d_in[27];
  const float* m1b = (const float*)d_in[28];
  const float* m2w = (const float*)d_in[29];
  const float* m2b = (const float*)d_in[30];
  float* ws = (float*)d_ws;
  float* out = (float*)d_out;

  k_prep<<<1, 256, 0, stream>>>(qt, qemb, ws);
  k_mint<<<(NE + 255) / 256, 256, 0, stream>>>(etime, ws);
  k_zero_ptr<<<(NW * (NN + 1) + 255) / 256, 256, 0, stream>>>(ws);
  {
    int total = NL * 2 * DD * DD + 4 * NFL * DD * DD + NFL * DD * NFFN + NFL * NFFN * DD +
                2 * DD * 2 * DD;
    k_transpose<<<(total + 255) / 256, 256, 0, stream>>>(linw, wq, wk, wv, wo, ffw1, ffw2,
                                                          m1w, ws);
  }
  k_rel<<<dim3(NR * DD / 256, NL), 256, 0, stream>>>(rlw, rlb, ws);
  k_hist<<<dim3((NE + 255) / 256, NW), 256, 0, stream>>>(eidx, ws);
  k_scan<<<NW, 256, 0, stream>>>(ws);
  k_curinit<<<(NW * NN + 255) / 256, 256, 0, stream>>>(ws);
  k_scatter<<<dim3((NE + 255) / 256, NW), 256, 0, stream>>>(eidx, etype, etime, ew, ws);

  float* X = ws + OFF_X;
  float* X2 = ws + OFF_X2;
  for (int w = 0; w < NW; ++w) {
    k_fill_init<<<NB * NN * DD / 256, 256, 0, stream>>>(X, ws);
    float* cur = X;
    float* nxt = X2;
    for (int l = 0; l < NL; ++l) {
      k_agg<<<NN / 4, 256, 0, stream>>>(tw, tb, cur, ws, w, l);
      k_gemm<<<NB * NN / 32, 256, 0, stream>>>(linb, lns, lnb, cur, nxt, ws, l);
      float* t = cur; cur = nxt; nxt = t;
    }
    k_gather<<<(NB * NNEG * DD + 255) / 256, 256, 0, stream>>>(pe, cur, ws, w);
  }
  k_xform<<<NB * NNEG, 192, 0, stream>>>(ffb1, ffb2, fln1s, fln1b, fln2s, fln2b, m1b, m2w,
                                          m2b, ws, out);
}

// Round 3
// 647.856 us; speedup vs baseline: 2.2394x; 1.0640x over previous
//
#include <hip/hip_runtime.h>
#include <hip/hip_bf16.h>
#include <cmath>

#define NB 4
#define NNEG 33
#define NN 10000
#define NE 100000
#define NW 3
#define DD 64
#define NL 3
#define NR 200
#define NFL 2
#define NFFN 256
#define LN_EPS 1e-5f

// ---- ws layout (float offsets) ----
#define OFF_QUERY 0                                   // NB*DD
#define OFF_H0    256                                 // NB ints
#define OFF_TSW   288                                 // NB*NNEG ints
#define OFF_MINT  448                                 // 1 int
#define OFF_REL   512                                 // NL*NB*NR*DD
#define OFF_LINT  (OFF_REL + NL*NB*NR*DD)             // NL*2*DD*DD
#define OFF_X     (OFF_LINT + NL*2*DD*DD)             // NB*NN*DD
#define OFF_AGG   (OFF_X + NB*NN*DD)                  // NB*NN*DD
#define OFF_TOK   (OFF_AGG + NB*NN*DD)                // NB*NNEG*NW*DD
#define OFF_X2    (OFF_TOK + NB*NNEG*NW*DD)           // NB*NN*DD
// int offsets (4B units)
#define IOFF_PTR  (OFF_X2 + NB*NN*DD)                 // NW*(NN+1) ints
#define IOFF_CUR  (IOFF_PTR + NW*(NN+1))              // NW*NN ints
#define IOFF_REC  ((IOFF_CUR + NW*NN + 3) & ~3)       // NW*NE*4 ints, 16B aligned

// ---------------- prep ----------------
__global__ void k_prep(const int* __restrict__ qt, const float* __restrict__ qemb,
                       float* __restrict__ ws) {
  int tid = threadIdx.x;
  if (tid < NB * DD) {
    int b = tid / DD, d = tid % DD;
    int h0 = qt[(b * NNEG + 0) * 3 + 0];
    bool itn = true;
    for (int j = 1; j < NNEG; ++j) itn = itn && (qt[(b * NNEG + j) * 3 + 0] == h0);
    int r0 = qt[(b * NNEG + 0) * 3 + 1] + (itn ? 0 : NR / 2);
    ws[OFF_QUERY + b * DD + d] = qemb[r0 * DD + d];
    if (d == 0) {
      int t0 = qt[(b * NNEG + 0) * 3 + 2];
      ((int*)ws)[OFF_H0 + b] = itn ? h0 : t0;
    }
  }
  if (tid < NB * NNEG) {
    int b = tid / NNEG, j = tid % NNEG;
    int h0 = qt[(b * NNEG + 0) * 3 + 0];
    bool itn = true;
    for (int jj = 1; jj < NNEG; ++jj) itn = itn && (qt[(b * NNEG + jj) * 3 + 0] == h0);
    int h = qt[(b * NNEG + j) * 3 + 0], t = qt[(b * NNEG + j) * 3 + 2];
    ((int*)ws)[OFF_TSW + tid] = itn ? t : h;
  }
  if (tid == 0) ((int*)ws)[OFF_MINT] = 0x7fffffff;
}

// ---------------- min over edge_time[0] ----------------
__global__ void k_mint(const int* __restrict__ etime, float* __restrict__ ws) {
  int i = blockIdx.x * blockDim.x + threadIdx.x;
  int v = (i < NE) ? etime[i] : 0x7fffffff;
  for (int m = 1; m < 64; m <<= 1) v = min(v, __shfl_xor(v, m));
  if ((threadIdx.x & 63) == 0) atomicMin(&((int*)ws)[OFF_MINT], v);
}

// ---------------- zero ptr array ----------------
__global__ void k_zero_ptr(float* __restrict__ ws) {
  int i = blockIdx.x * 256 + threadIdx.x;
  if (i < NW * (NN + 1)) ((int*)ws)[IOFF_PTR + i] = 0;
}

// ---------------- histogram of dst ----------------
__global__ void k_hist(const int* __restrict__ eidx, float* __restrict__ ws) {
  int e = blockIdx.x * 256 + threadIdx.x, w = blockIdx.y;
  if (e >= NE) return;
  int dst = eidx[(w * 2 + 1) * NE + e];
  atomicAdd(&((int*)ws)[IOFF_PTR + w * (NN + 1) + dst + 1], 1);
}

// ---------------- inclusive scan -> ptr (one block per w) ----------------
__global__ void k_scan(float* __restrict__ ws) {
  int w = blockIdx.x;
  int* p = (int*)ws + IOFF_PTR + w * (NN + 1);
  __shared__ int wsum[4];
  __shared__ int runv;
  if (threadIdx.x == 0) runv = 0;
  __syncthreads();
  int lane = threadIdx.x & 63, wv = threadIdx.x >> 6;
  for (int base = 0; base < NN + 1; base += 256) {
    int i = base + threadIdx.x;
    int v = (i <= NN) ? p[i] : 0;
    for (int off = 1; off < 64; off <<= 1) {
      int t = __shfl_up(v, off);
      if (lane >= off) v += t;
    }
    if (lane == 63) wsum[wv] = v;
    __syncthreads();
    int add = runv;
    for (int u = 0; u < wv; ++u) add += wsum[u];
    v += add;
    if (i <= NN) p[i] = v;
    __syncthreads();
    if (threadIdx.x == 255) runv = v;
    __syncthreads();
  }
}

// ---------------- cursor init ----------------
__global__ void k_curinit(float* __restrict__ ws) {
  int i = blockIdx.x * 256 + threadIdx.x;
  if (i >= NW * NN) return;
  int w = i / NN, n = i % NN;
  ((int*)ws)[IOFF_CUR + i] = ((int*)ws)[IOFF_PTR + w * (NN + 1) + n];
}

// ---------------- scatter edges into CSR records {src, et, dt, weight} ----------------
__global__ void k_scatter(const int* __restrict__ eidx, const int* __restrict__ etype,
                          const int* __restrict__ etime, const float* __restrict__ eweight,
                          float* __restrict__ ws) {
  int e = blockIdx.x * 256 + threadIdx.x, w = blockIdx.y;
  if (e >= NE) return;
  int* wsi = (int*)ws;
  int dst = eidx[(w * 2 + 1) * NE + e];
  int pos = atomicAdd(&wsi[IOFF_CUR + w * NN + dst], 1);
  float dt = (float)etime[w * NE + e] - (float)wsi[OFF_MINT];
  int4 rec;
  rec.x = eidx[(w * 2 + 0) * NE + e];
  rec.y = etype[w * NE + e];
  rec.z = __float_as_int(dt);
  rec.w = __float_as_int(eweight[w * NE + e]);
  ((int4*)(wsi + IOFF_REC))[(size_t)w * NE + pos] = rec;
}

// ---------------- transpose lin_w only ----------------
__global__ void k_transpose(const float* __restrict__ lin_w, float* __restrict__ ws) {
  int idx = blockIdx.x * blockDim.x + threadIdx.x;
  if (idx < NL * 2 * DD * DD) {  // linT[l][k][d] = lin_w[l][d][k]
    int l = idx / (2 * DD * DD), r = idx % (2 * DD * DD), k = r / DD, d = r % DD;
    ws[OFF_LINT + idx] = lin_w[(l * DD + d) * 2 * DD + k];
  }
}

// ---------------- rel = query @ rel_lin_w.T + b ----------------
__global__ void k_rel(const float* __restrict__ rlw, const float* __restrict__ rlb,
                      float* __restrict__ ws) {
  int l = blockIdx.y;
  int rd = blockIdx.x * blockDim.x + threadIdx.x;
  const float4* wrow = (const float4*)(rlw + ((size_t)(l * NR * DD + rd)) * DD);
  float4 wreg[16];
#pragma unroll
  for (int kk = 0; kk < 16; ++kk) wreg[kk] = wrow[kk];
  float bias = rlb[l * NR * DD + rd];
  for (int b = 0; b < NB; ++b) {
    const float4* q4 = (const float4*)(ws + OFF_QUERY + b * DD);
    float acc = 0.f;
#pragma unroll
    for (int kk = 0; kk < 16; ++kk) {
      float4 q = q4[kk];
      acc += q.x * wreg[kk].x + q.y * wreg[kk].y + q.z * wreg[kk].z + q.w * wreg[kk].w;
    }
    ws[OFF_REL + (l * NB + b) * NR * DD + rd] = acc + bias;
  }
}

// ---------------- fill buf with init pattern ----------------
__global__ void k_fill_init(float* __restrict__ buf, const float* __restrict__ ws) {
  int i = blockIdx.x * 256 + threadIdx.x;
  int b = i / (NN * DD);
  int r = i % (NN * DD);
  int n = r / DD, d = r % DD;
  int h0 = ((const int*)ws)[OFF_H0 + b];
  buf[i] = (n == h0) ? ws[OFF_QUERY + b * DD + d] : 0.f;
}

// ---------------- CSR gather aggregation: wave per node, 4 batches inside ----------------
__global__ __launch_bounds__(256) void k_agg(const float* __restrict__ tw,
                                             const float* __restrict__ tb,
                                             const float* __restrict__ xcur,
                                             float* __restrict__ ws, int w, int l) {
  int wv = threadIdx.x >> 6, d = threadIdx.x & 63;
  int n = blockIdx.x * 4 + wv;
  const int* wsi = (const int*)ws;
  int p0 = wsi[IOFF_PTR + w * (NN + 1) + n];
  int p1 = wsi[IOFF_PTR + w * (NN + 1) + n + 1];
  const int4* recs = ((const int4*)(wsi + IOFF_REC)) + (size_t)w * NE;
  const float* twl = tw + l * NR * DD;
  const float* tbl = tb + l * NR * DD;
  const float* rell = ws + OFF_REL + l * NB * NR * DD;
  float a0 = (n == wsi[OFF_H0 + 0]) ? ws[OFF_QUERY + 0 * DD + d] : 0.f;
  float a1 = (n == wsi[OFF_H0 + 1]) ? ws[OFF_QUERY + 1 * DD + d] : 0.f;
  float a2 = (n == wsi[OFF_H0 + 2]) ? ws[OFF_QUERY + 2 * DD + d] : 0.f;
  float a3 = (n == wsi[OFF_H0 + 3]) ? ws[OFF_QUERY + 3 * DD + d] : 0.f;
  for (int j = p0; j < p1; ++j) {
    int4 rec = recs[j];
    int src = rec.x, et = rec.y;
    float dt = __int_as_float(rec.z), wgt = __int_as_float(rec.w);
    float te = cosf(fmaf(dt, twl[et * DD + d], tbl[et * DD + d])) * wgt;
    const float* xb = xcur + src * DD + d;
    const float* rb = rell + et * DD + d;
    a0 = fmaf(xb[0 * NN * DD] * rb[0 * NR * DD], te, a0);
    a1 = fmaf(xb[1 * NN * DD] * rb[1 * NR * DD], te, a1);
    a2 = fmaf(xb[2 * NN * DD] * rb[2 * NR * DD], te, a2);
    a3 = fmaf(xb[3 * NN * DD] * rb[3 * NR * DD], te, a3);
  }
  float* agg = ws + OFF_AGG;
  agg[(0 * NN + n) * DD + d] = a0;
  agg[(1 * NN + n) * DD + d] = a1;
  agg[(2 * NN + n) * DD + d] = a2;
  agg[(3 * NN + n) * DD + d] = a3;
}

// ---------------- node GEMM + LN + residual; wave = 8 rows x 64 cols ----------------
__global__ __launch_bounds__(256) void k_gemm(const float* __restrict__ linb,
                                              const float* __restrict__ lns,
                                              const float* __restrict__ lnb,
                                              const float* __restrict__ xsrc,
                                              float* __restrict__ xdst,
                                              const float* __restrict__ ws, int l) {
  int wv = __builtin_amdgcn_readfirstlane(threadIdx.x >> 6);
  int c = threadIdx.x & 63;
  int row0 = blockIdx.x * 32 + wv * 8;
  const float* WT = ws + OFF_LINT + l * 2 * DD * DD;  // [128][64]
  const float* aggsrc = ws + OFF_AGG;
  float bias = linb[l * DD + c];
  float acc[8];
#pragma unroll
  for (int r = 0; r < 8; ++r) acc[r] = bias;
  for (int kk = 0; kk < 16; ++kk) {
    float w0 = WT[(4 * kk + 0) * DD + c];
    float w1 = WT[(4 * kk + 1) * DD + c];
    float w2 = WT[(4 * kk + 2) * DD + c];
    float w3 = WT[(4 * kk + 3) * DD + c];
#pragma unroll
    for (int r = 0; r < 8; ++r) {
      float4 xv = *(const float4*)(xsrc + (size_t)(row0 + r) * DD + 4 * kk);
      acc[r] = fmaf(xv.x, w0, acc[r]);
      acc[r] = fmaf(xv.y, w1, acc[r]);
      acc[r] = fmaf(xv.z, w2, acc[r]);
      acc[r] = fmaf(xv.w, w3, acc[r]);
    }
  }
  for (int kk = 0; kk < 16; ++kk) {
    float w0 = WT[(64 + 4 * kk + 0) * DD + c];
    float w1 = WT[(64 + 4 * kk + 1) * DD + c];
    float w2 = WT[(64 + 4 * kk + 2) * DD + c];
    float w3 = WT[(64 + 4 * kk + 3) * DD + c];
#pragma unroll
    for (int r = 0; r < 8; ++r) {
      float4 xv = *(const float4*)(aggsrc + (size_t)(row0 + r) * DD + 4 * kk);
      acc[r] = fmaf(xv.x, w0, acc[r]);
      acc[r] = fmaf(xv.y, w1, acc[r]);
      acc[r] = fmaf(xv.z, w2, acc[r]);
      acc[r] = fmaf(xv.w, w3, acc[r]);
    }
  }
  float sc = lns[l * DD + c], bc = lnb[l * DD + c];
#pragma unroll
  for (int r = 0; r < 8; ++r) {
    float v = acc[r];
    float s = v;
    for (int m = 1; m < 64; m <<= 1) s += __shfl_xor(s, m);
    float mean = s * (1.f / 64.f);
    float cv = v - mean;
    float vv = cv * cv;
    for (int m = 1; m < 64; m <<= 1) vv += __shfl_xor(vv, m);
    vv *= (1.f / 64.f);
    float y = cv * __frsqrt_rn(vv + LN_EPS) * sc + bc;
    y = fmaxf(y, 0.f);
    float xo = xsrc[(size_t)(row0 + r) * DD + c];
    xdst[(size_t)(row0 + r) * DD + c] = xo + y;
  }
}

// ---------------- gather tail features into tokens (+pe) ----------------
__global__ void k_gather(const float* __restrict__ pe, const float* __restrict__ xfin,
                         float* __restrict__ ws, int w) {
  int i = blockIdx.x * 256 + threadIdx.x;
  if (i >= NB * NNEG * DD) return;
  int bj = i / DD, d = i % DD;
  int b = bj / NNEG;
  int t = ((const int*)ws)[OFF_TSW + bj];
  ws[OFF_TOK + bj * NW * DD + w * DD + d] = xfin[(b * NN + t) * DD + d] + pe[w * DD + d];
}

// ---------------- transformer + final MLP (row-major weight reads, float4/thread) ----------------
__global__ void k_xform(const float* __restrict__ wq, const float* __restrict__ wk,
                        const float* __restrict__ wv, const float* __restrict__ wo,
                        const float* __restrict__ ffw1, const float* __restrict__ ffb1,
                        const float* __restrict__ ffw2, const float* __restrict__ ffb2,
                        const float* __restrict__ fln1s, const float* __restrict__ fln1b,
                        const float* __restrict__ fln2s, const float* __restrict__ fln2b,
                        const float* __restrict__ m1w, const float* __restrict__ m1b,
                        const float* __restrict__ m2w, const float* __restrict__ m2b,
                        float* __restrict__ ws, float* __restrict__ out) {
  __shared__ float tok[NW][DD], kb[NW][DD], vb[NW][DD], hb[NW][NFFN], feat[2 * DD];
  __shared__ float redbuf[3];
  int tk = threadIdx.x / 64, d = threadIdx.x & 63;
  int row = blockIdx.x, b = row / NNEG;
  tok[tk][d] = ws[OFF_TOK + row * NW * DD + tk * DD + d];
  __syncthreads();
  for (int f = 0; f < NFL; ++f) {
    // ---- QKV: thread d reads its contiguous weight rows as float4 ----
    const float4* WQ4 = (const float4*)(wq + (size_t)(f * DD + d) * DD);
    const float4* WK4 = (const float4*)(wk + (size_t)(f * DD + d) * DD);
    const float4* WV4 = (const float4*)(wv + (size_t)(f * DD + d) * DD);
    float qd = 0.f, kd = 0.f, vd = 0.f;
#pragma unroll
    for (int kk = 0; kk < 16; ++kk) {
      float4 tv = *(const float4*)&tok[tk][4 * kk];
      float4 aq = WQ4[kk], ak = WK4[kk], av = WV4[kk];
      qd += tv.x * aq.x + tv.y * aq.y + tv.z * aq.z + tv.w * aq.w;
      kd += tv.x * ak.x + tv.y * ak.y + tv.z * ak.z + tv.w * ak.w;
      vd += tv.x * av.x + tv.y * av.y + tv.z * av.z + tv.w * av.w;
    }
    kb[tk][d] = kd;
    vb[tk][d] = vd;
    __syncthreads();
    // ---- attention (head = d>>4, reduce within 16 lanes) ----
    float sc[NW];
#pragma unroll
    for (int j = 0; j < NW; ++j) {
      float p = qd * kb[j][d];
      p += __shfl_xor(p, 1);
      p += __shfl_xor(p, 2);
      p += __shfl_xor(p, 4);
      p += __shfl_xor(p, 8);
      sc[j] = p * 0.25f;  // 1/sqrt(16)
    }
    float mx = fmaxf(sc[0], fmaxf(sc[1], sc[2]));
    float e0 = expf(sc[0] - mx), e1 = expf(sc[1] - mx), e2 = expf(sc[2] - mx);
    float inv = 1.f / (e0 + e1 + e2);
    float od = (e0 * vb[0][d] + e1 * vb[1][d] + e2 * vb[2][d]) * inv;
    __syncthreads();        // all waves done reading kb/vb
    kb[tk][d] = od;         // reuse kb as o-buffer (wave-private from here)
    // ---- o @ wo.T ----
    const float4* WO4 = (const float4*)(wo + (size_t)(f * DD + d) * DD);
    float ao = 0.f;
#pragma unroll
    for (int kk = 0; kk < 16; ++kk) {
      float4 ov = *(const float4*)&kb[tk][4 * kk];
      float4 w4 = WO4[kk];
      ao += ov.x * w4.x + ov.y * w4.y + ov.z * w4.z + ov.w * w4.w;
    }
    float t1 = tok[tk][d] + ao;
    // ---- LN1 ----
    float s = t1;
    for (int m = 1; m < 64; m <<= 1) s += __shfl_xor(s, m);
    float mean = s * (1.f / 64.f);
    float cv = t1 - mean;
    float v = cv * cv;
    for (int m = 1; m < 64; m <<= 1) v += __shfl_xor(v, m);
    v *= (1.f / 64.f);
    t1 = cv * __frsqrt_rn(v + LN_EPS) * fln1s[f * DD + d] + fln1b[f * DD + d];
    tok[tk][d] = t1;  // wave-private row
    // ---- FFN1: 4 hidden outputs per thread (u = d + 64*uu) ----
    float h[4];
#pragma unroll
    for (int uu = 0; uu < 4; ++uu) h[uu] = ffb1[f * NFFN + d + 64 * uu];
    const float4* F1r0 = (const float4*)(ffw1 + (size_t)(f * NFFN + d + 0) * DD);
    const float4* F1r1 = (const float4*)(ffw1 + (size_t)(f * NFFN + d + 64) * DD);
    const float4* F1r2 = (const float4*)(ffw1 + (size_t)(f * NFFN + d + 128) * DD);
    const float4* F1r3 = (const float4*)(ffw1 + (size_t)(f * NFFN + d + 192) * DD);
#pragma unroll
    for (int kk = 0; kk < 16; ++kk) {
      float4 tv = *(const float4*)&tok[tk][4 * kk];
      float4 w0 = F1r0[kk], w1 = F1r1[kk], w2 = F1r2[kk], w3 = F1r3[kk];
      h[0] += tv.x * w0.x + tv.y * w0.y + tv.z * w0.z + tv.w * w0.w;
      h[1] += tv.x * w1.x + tv.y * w1.y + tv.z * w1.z + tv.w * w1.w;
      h[2] += tv.x * w2.x + tv.y * w2.y + tv.z * w2.z + tv.w * w2.w;
      h[3] += tv.x * w3.x + tv.y * w3.y + tv.z * w3.z + tv.w * w3.w;
    }
#pragma unroll
    for (int uu = 0; uu < 4; ++uu) hb[tk][d + 64 * uu] = fmaxf(h[uu], 0.f);
    // ---- FFN2: 256-deep dot, thread reads contiguous row of ffw2 ----
    const float4* F2r = (const float4*)(ffw2 + (size_t)(f * DD + d) * NFFN);
    float ff = ffb2[f * DD + d];
#pragma unroll 8
    for (int kk = 0; kk < 64; ++kk) {
      float4 hv = *(const float4*)&hb[tk][4 * kk];
      float4 w4 = F2r[kk];
      ff += hv.x * w4.x + hv.y * w4.y + hv.z * w4.z + hv.w * w4.w;
    }
    float t2 = t1 + ff;
    // ---- LN2 ----
    s = t2;
    for (int m = 1; m < 64; m <<= 1) s += __shfl_xor(s, m);
    mean = s * (1.f / 64.f);
    cv = t2 - mean;
    v = cv * cv;
    for (int m = 1; m < 64; m <<= 1) v += __shfl_xor(v, m);
    v *= (1.f / 64.f);
    t2 = cv * __frsqrt_rn(v + LN_EPS) * fln2s[f * DD + d] + fln2b[f * DD + d];
    tok[tk][d] = t2;
    __syncthreads();
  }
  // ---- final MLP: 128 threads, one hidden unit each ----
  if (tk == 2) {
    feat[d] = tok[2][d];
    feat[DD + d] = ws[OFF_QUERY + b * DD + d];
  }
  __syncthreads();
  int hh = threadIdx.x;
  float partial = 0.f;
  if (hh < 2 * DD) {
    const float4* M1r = (const float4*)(m1w + (size_t)hh * 2 * DD);
    float acc = m1b[hh];
#pragma unroll
    for (int kk = 0; kk < 32; ++kk) {
      float4 fv = *(const float4*)&feat[4 * kk];
      float4 w4 = M1r[kk];
      acc += fv.x * w4.x + fv.y * w4.y + fv.z * w4.z + fv.w * w4.w;
    }
    acc = fmaxf(acc, 0.f);
    partial = acc * m2w[hh];
  }
  for (int m = 1; m < 64; m <<= 1) partial += __shfl_xor(partial, m);
  if ((threadIdx.x & 63) == 0) redbuf[threadIdx.x >> 6] = partial;
  __syncthreads();
  if (threadIdx.x == 0) out[row] = redbuf[0] + redbuf[1] + m2b[0];
}

extern "C" void kernel_launch(void* const* d_in, const int* in_sizes, int n_in,
                              void* d_out, int out_size, void* d_ws, size_t ws_size,
                              hipStream_t stream) {
  const int* qt = (const int*)d_in[0];
  const int* eidx = (const int*)d_in[1];
  const int* etype = (const int*)d_in[2];
  const int* etime = (const int*)d_in[3];
  const float* qemb = (const float*)d_in[4];
  const float* ew = (const float*)d_in[5];
  const float* rlw = (const float*)d_in[6];
  const float* rlb = (const float*)d_in[7];
  const float* tw = (const float*)d_in[8];
  const float* tb = (const float*)d_in[9];
  const float* linw = (const float*)d_in[10];
  const float* linb = (const float*)d_in[11];
  const float* lns = (const float*)d_in[12];
  const float* lnb = (const float*)d_in[13];
  const float* pe = (const float*)d_in[14];
  const float* wq = (const float*)d_in[15];
  const float* wk = (const float*)d_in[16];
  const float* wv = (const float*)d_in[17];
  const float* wo = (const float*)d_in[18];
  const float* ffw1 = (const float*)d_in[19];
  const float* ffb1 = (const float*)d_in[20];
  const float* ffw2 = (const float*)d_in[21];
  const float* ffb2 = (const float*)d_in[22];
  const float* fln1s = (const float*)d_in[23];
  const float* fln1b = (const float*)d_in[24];
  const float* fln2s = (const float*)d_in[25];
  const float* fln2b = (const float*)d_in[26];
  const float* m1w = (const float*)d_in[27];
  const float* m1b = (const float*)d_in[28];
  const float* m2w = (const float*)d_in[29];
  const float* m2b = (const float*)d_in[30];
  float* ws = (float*)d_ws;
  float* out = (float*)d_out;

  k_prep<<<1, 256, 0, stream>>>(qt, qemb, ws);
  k_mint<<<(NE + 255) / 256, 256, 0, stream>>>(etime, ws);
  k_zero_ptr<<<(NW * (NN + 1) + 255) / 256, 256, 0, stream>>>(ws);
  k_transpose<<<(NL * 2 * DD * DD + 255) / 256, 256, 0, stream>>>(linw, ws);
  k_rel<<<dim3(NR * DD / 256, NL), 256, 0, stream>>>(rlw, rlb, ws);
  k_hist<<<dim3((NE + 255) / 256, NW), 256, 0, stream>>>(eidx, ws);
  k_scan<<<NW, 256, 0, stream>>>(ws);
  k_curinit<<<(NW * NN + 255) / 256, 256, 0, stream>>>(ws);
  k_scatter<<<dim3((NE + 255) / 256, NW), 256, 0, stream>>>(eidx, etype, etime, ew, ws);

  float* X = ws + OFF_X;
  float* X2 = ws + OFF_X2;
  for (int w = 0; w < NW; ++w) {
    k_fill_init<<<NB * NN * DD / 256, 256, 0, stream>>>(X, ws);
    float* cur = X;
    float* nxt = X2;
    for (int l = 0; l < NL; ++l) {
      k_agg<<<NN / 4, 256, 0, stream>>>(tw, tb, cur, ws, w, l);
      k_gemm<<<NB * NN / 32, 256, 0, stream>>>(linb, lns, lnb, cur, nxt, ws, l);
      float* t = cur; cur = nxt; nxt = t;
    }
    k_gather<<<(NB * NNEG * DD + 255) / 256, 256, 0, stream>>>(pe, cur, ws, w);
  }
  k_xform<<<NB * NNEG, 192, 0, stream>>>(wq, wk, wv, wo, ffw1, ffb1, ffw2, ffb2, fln1s,
                                          fln1b, fln2s, fln2b, m1w, m1b, m2w, m2b, ws, out);
}

// Round 4
// 546.602 us; speedup vs baseline: 2.6542x; 1.1852x over previous
//
#include <hip/hip_runtime.h>
#include <hip/hip_bf16.h>
#include <cmath>

#define NB 4
#define NNEG 33
#define NN 10000
#define NE 100000
#define NW 3
#define DD 64
#define NL 3
#define NR 200
#define NFL 2
#define NFFN 256
#define LN_EPS 1e-5f
#define RPB 4   // rows per k_xform block (132 = 33*4)

// ---- ws layout (float offsets) ----
#define OFF_QUERY 0                                   // NB*DD
#define OFF_H0    256                                 // NB ints
#define OFF_TSW   288                                 // NB*NNEG ints
#define OFF_MINT  448                                 // 1 int
#define OFF_REL   512                                 // NL*NB*NR*DD
#define OFF_LINT  (OFF_REL + NL*NB*NR*DD)             // NL*2*DD*DD
#define OFF_X     (OFF_LINT + NL*2*DD*DD)             // NB*NN*DD
#define OFF_AGG   (OFF_X + NB*NN*DD)                  // NB*NN*DD
#define OFF_TOK   (OFF_AGG + NB*NN*DD)                // NB*NNEG*NW*DD
#define OFF_X2    (OFF_TOK + NB*NNEG*NW*DD)           // NB*NN*DD
// int offsets (4B units)
#define IOFF_PTR  (OFF_X2 + NB*NN*DD)                 // NW*(NN+1) ints
#define IOFF_CUR  (IOFF_PTR + NW*(NN+1))              // NW*NN ints
#define IOFF_REC  ((IOFF_CUR + NW*NN + 3) & ~3)       // NW*NE*4 ints, 16B aligned

// ---------------- prep ----------------
__global__ void k_prep(const int* __restrict__ qt, const float* __restrict__ qemb,
                       float* __restrict__ ws) {
  int tid = threadIdx.x;
  if (tid < NB * DD) {
    int b = tid / DD, d = tid % DD;
    int h0 = qt[(b * NNEG + 0) * 3 + 0];
    bool itn = true;
    for (int j = 1; j < NNEG; ++j) itn = itn && (qt[(b * NNEG + j) * 3 + 0] == h0);
    int r0 = qt[(b * NNEG + 0) * 3 + 1] + (itn ? 0 : NR / 2);
    ws[OFF_QUERY + b * DD + d] = qemb[r0 * DD + d];
    if (d == 0) {
      int t0 = qt[(b * NNEG + 0) * 3 + 2];
      ((int*)ws)[OFF_H0 + b] = itn ? h0 : t0;
    }
  }
  if (tid < NB * NNEG) {
    int b = tid / NNEG, j = tid % NNEG;
    int h0 = qt[(b * NNEG + 0) * 3 + 0];
    bool itn = true;
    for (int jj = 1; jj < NNEG; ++jj) itn = itn && (qt[(b * NNEG + jj) * 3 + 0] == h0);
    int h = qt[(b * NNEG + j) * 3 + 0], t = qt[(b * NNEG + j) * 3 + 2];
    ((int*)ws)[OFF_TSW + tid] = itn ? t : h;
  }
  if (tid == 0) ((int*)ws)[OFF_MINT] = 0x7fffffff;
}

// ---------------- min over edge_time[0] ----------------
__global__ void k_mint(const int* __restrict__ etime, float* __restrict__ ws) {
  int i = blockIdx.x * blockDim.x + threadIdx.x;
  int v = (i < NE) ? etime[i] : 0x7fffffff;
  for (int m = 1; m < 64; m <<= 1) v = min(v, __shfl_xor(v, m));
  if ((threadIdx.x & 63) == 0) atomicMin(&((int*)ws)[OFF_MINT], v);
}

// ---------------- zero ptr array ----------------
__global__ void k_zero_ptr(float* __restrict__ ws) {
  int i = blockIdx.x * 256 + threadIdx.x;
  if (i < NW * (NN + 1)) ((int*)ws)[IOFF_PTR + i] = 0;
}

// ---------------- histogram of dst ----------------
__global__ void k_hist(const int* __restrict__ eidx, float* __restrict__ ws) {
  int e = blockIdx.x * 256 + threadIdx.x, w = blockIdx.y;
  if (e >= NE) return;
  int dst = eidx[(w * 2 + 1) * NE + e];
  atomicAdd(&((int*)ws)[IOFF_PTR + w * (NN + 1) + dst + 1], 1);
}

// ---------------- inclusive scan -> ptr (one block per w) ----------------
__global__ void k_scan(float* __restrict__ ws) {
  int w = blockIdx.x;
  int* p = (int*)ws + IOFF_PTR + w * (NN + 1);
  __shared__ int wsum[4];
  __shared__ int runv;
  if (threadIdx.x == 0) runv = 0;
  __syncthreads();
  int lane = threadIdx.x & 63, wv = threadIdx.x >> 6;
  for (int base = 0; base < NN + 1; base += 256) {
    int i = base + threadIdx.x;
    int v = (i <= NN) ? p[i] : 0;
    for (int off = 1; off < 64; off <<= 1) {
      int t = __shfl_up(v, off);
      if (lane >= off) v += t;
    }
    if (lane == 63) wsum[wv] = v;
    __syncthreads();
    int add = runv;
    for (int u = 0; u < wv; ++u) add += wsum[u];
    v += add;
    if (i <= NN) p[i] = v;
    __syncthreads();
    if (threadIdx.x == 255) runv = v;
    __syncthreads();
  }
}

// ---------------- cursor init ----------------
__global__ void k_curinit(float* __restrict__ ws) {
  int i = blockIdx.x * 256 + threadIdx.x;
  if (i >= NW * NN) return;
  int w = i / NN, n = i % NN;
  ((int*)ws)[IOFF_CUR + i] = ((int*)ws)[IOFF_PTR + w * (NN + 1) + n];
}

// ---------------- scatter edges into CSR records {src, et, dt, weight} ----------------
__global__ void k_scatter(const int* __restrict__ eidx, const int* __restrict__ etype,
                          const int* __restrict__ etime, const float* __restrict__ eweight,
                          float* __restrict__ ws) {
  int e = blockIdx.x * 256 + threadIdx.x, w = blockIdx.y;
  if (e >= NE) return;
  int* wsi = (int*)ws;
  int dst = eidx[(w * 2 + 1) * NE + e];
  int pos = atomicAdd(&wsi[IOFF_CUR + w * NN + dst], 1);
  float dt = (float)etime[w * NE + e] - (float)wsi[OFF_MINT];
  int4 rec;
  rec.x = eidx[(w * 2 + 0) * NE + e];
  rec.y = etype[w * NE + e];
  rec.z = __float_as_int(dt);
  rec.w = __float_as_int(eweight[w * NE + e]);
  ((int4*)(wsi + IOFF_REC))[(size_t)w * NE + pos] = rec;
}

// ---------------- transpose lin_w only ----------------
__global__ void k_transpose(const float* __restrict__ lin_w, float* __restrict__ ws) {
  int idx = blockIdx.x * blockDim.x + threadIdx.x;
  if (idx < NL * 2 * DD * DD) {  // linT[l][k][d] = lin_w[l][d][k]
    int l = idx / (2 * DD * DD), r = idx % (2 * DD * DD), k = r / DD, d = r % DD;
    ws[OFF_LINT + idx] = lin_w[(l * DD + d) * 2 * DD + k];
  }
}

// ---------------- rel = query @ rel_lin_w.T + b ----------------
__global__ void k_rel(const float* __restrict__ rlw, const float* __restrict__ rlb,
                      float* __restrict__ ws) {
  int l = blockIdx.y;
  int rd = blockIdx.x * blockDim.x + threadIdx.x;
  const float4* wrow = (const float4*)(rlw + ((size_t)(l * NR * DD + rd)) * DD);
  float4 wreg[16];
#pragma unroll
  for (int kk = 0; kk < 16; ++kk) wreg[kk] = wrow[kk];
  float bias = rlb[l * NR * DD + rd];
  for (int b = 0; b < NB; ++b) {
    const float4* q4 = (const float4*)(ws + OFF_QUERY + b * DD);
    float acc = 0.f;
#pragma unroll
    for (int kk = 0; kk < 16; ++kk) {
      float4 q = q4[kk];
      acc += q.x * wreg[kk].x + q.y * wreg[kk].y + q.z * wreg[kk].z + q.w * wreg[kk].w;
    }
    ws[OFF_REL + (l * NB + b) * NR * DD + rd] = acc + bias;
  }
}

// ---------------- CSR gather aggregation: wave per node, 4 batches inside ----------------
__global__ __launch_bounds__(256) void k_agg(const float* __restrict__ tw,
                                             const float* __restrict__ tb,
                                             const float* __restrict__ xcur,
                                             float* __restrict__ ws, int w, int l,
                                             int init0) {
  int wv = threadIdx.x >> 6, d = threadIdx.x & 63;
  int n = blockIdx.x * 4 + wv;
  const int* wsi = (const int*)ws;
  int p0 = wsi[IOFF_PTR + w * (NN + 1) + n];
  int p1 = wsi[IOFF_PTR + w * (NN + 1) + n + 1];
  const int4* recs = ((const int4*)(wsi + IOFF_REC)) + (size_t)w * NE;
  const float* twl = tw + l * NR * DD;
  const float* tbl = tb + l * NR * DD;
  const float* rell = ws + OFF_REL + l * NB * NR * DD;
  int h00 = wsi[OFF_H0 + 0], h01 = wsi[OFF_H0 + 1];
  int h02 = wsi[OFF_H0 + 2], h03 = wsi[OFF_H0 + 3];
  float a0 = (n == h00) ? ws[OFF_QUERY + 0 * DD + d] : 0.f;
  float a1 = (n == h01) ? ws[OFF_QUERY + 1 * DD + d] : 0.f;
  float a2 = (n == h02) ? ws[OFF_QUERY + 2 * DD + d] : 0.f;
  float a3 = (n == h03) ? ws[OFF_QUERY + 3 * DD + d] : 0.f;
  if (init0) {
    // x == init: only edges with src == h0[b] contribute (wave-uniform test)
    for (int j = p0; j < p1; ++j) {
      int4 rec = recs[j];
      int src = rec.x;
      if (!((src == h00) | (src == h01) | (src == h02) | (src == h03))) continue;
      int et = rec.y;
      float dt = __int_as_float(rec.z), wgt = __int_as_float(rec.w);
      float te = cosf(fmaf(dt, twl[et * DD + d], tbl[et * DD + d])) * wgt;
      const float* rb = rell + et * DD + d;
      if (src == h00) a0 = fmaf(ws[OFF_QUERY + 0 * DD + d] * rb[0 * NR * DD], te, a0);
      if (src == h01) a1 = fmaf(ws[OFF_QUERY + 1 * DD + d] * rb[1 * NR * DD], te, a1);
      if (src == h02) a2 = fmaf(ws[OFF_QUERY + 2 * DD + d] * rb[2 * NR * DD], te, a2);
      if (src == h03) a3 = fmaf(ws[OFF_QUERY + 3 * DD + d] * rb[3 * NR * DD], te, a3);
    }
  } else {
    for (int j = p0; j < p1; ++j) {
      int4 rec = recs[j];
      int src = rec.x, et = rec.y;
      float dt = __int_as_float(rec.z), wgt = __int_as_float(rec.w);
      float te = cosf(fmaf(dt, twl[et * DD + d], tbl[et * DD + d])) * wgt;
      const float* xb = xcur + src * DD + d;
      const float* rb = rell + et * DD + d;
      a0 = fmaf(xb[0 * NN * DD] * rb[0 * NR * DD], te, a0);
      a1 = fmaf(xb[1 * NN * DD] * rb[1 * NR * DD], te, a1);
      a2 = fmaf(xb[2 * NN * DD] * rb[2 * NR * DD], te, a2);
      a3 = fmaf(xb[3 * NN * DD] * rb[3 * NR * DD], te, a3);
    }
  }
  float* agg = ws + OFF_AGG;
  agg[(0 * NN + n) * DD + d] = a0;
  agg[(1 * NN + n) * DD + d] = a1;
  agg[(2 * NN + n) * DD + d] = a2;
  agg[(3 * NN + n) * DD + d] = a3;
}

// ---------------- node GEMM + LN + residual; wave = 8 rows x 64 cols ----------------
__global__ __launch_bounds__(256) void k_gemm(const float* __restrict__ linb,
                                              const float* __restrict__ lns,
                                              const float* __restrict__ lnb,
                                              const float* __restrict__ xsrc,
                                              float* __restrict__ xdst,
                                              const float* __restrict__ ws, int l,
                                              int init0) {
  int wv = __builtin_amdgcn_readfirstlane(threadIdx.x >> 6);
  int c = threadIdx.x & 63;
  int row0 = blockIdx.x * 32 + wv * 8;
  const float* WT = ws + OFF_LINT + l * 2 * DD * DD;  // [128][64]
  const float* aggsrc = ws + OFF_AGG;
  const int* wsi = (const int*)ws;
  int b = row0 / NN;           // wave-uniform (8-row groups never straddle b)
  int n0 = row0 - b * NN;
  int h0b = wsi[OFF_H0 + b];
  float bias = linb[l * DD + c];
  float acc[8];
#pragma unroll
  for (int r = 0; r < 8; ++r) acc[r] = bias;
  if (init0) {
    // x == init: only the h0 row has a nonzero x-part
#pragma unroll
    for (int r = 0; r < 8; ++r) {
      if (n0 + r == h0b) {
        const float4* q4 = (const float4*)(ws + OFF_QUERY + b * DD);
        for (int kk = 0; kk < 16; ++kk) {
          float4 q = q4[kk];
          acc[r] = fmaf(q.x, WT[(4 * kk + 0) * DD + c], acc[r]);
          acc[r] = fmaf(q.y, WT[(4 * kk + 1) * DD + c], acc[r]);
          acc[r] = fmaf(q.z, WT[(4 * kk + 2) * DD + c], acc[r]);
          acc[r] = fmaf(q.w, WT[(4 * kk + 3) * DD + c], acc[r]);
        }
      }
    }
  } else {
    for (int kk = 0; kk < 16; ++kk) {
      float w0 = WT[(4 * kk + 0) * DD + c];
      float w1 = WT[(4 * kk + 1) * DD + c];
      float w2 = WT[(4 * kk + 2) * DD + c];
      float w3 = WT[(4 * kk + 3) * DD + c];
#pragma unroll
      for (int r = 0; r < 8; ++r) {
        float4 xv = *(const float4*)(xsrc + (size_t)(row0 + r) * DD + 4 * kk);
        acc[r] = fmaf(xv.x, w0, acc[r]);
        acc[r] = fmaf(xv.y, w1, acc[r]);
        acc[r] = fmaf(xv.z, w2, acc[r]);
        acc[r] = fmaf(xv.w, w3, acc[r]);
      }
    }
  }
  for (int kk = 0; kk < 16; ++kk) {
    float w0 = WT[(64 + 4 * kk + 0) * DD + c];
    float w1 = WT[(64 + 4 * kk + 1) * DD + c];
    float w2 = WT[(64 + 4 * kk + 2) * DD + c];
    float w3 = WT[(64 + 4 * kk + 3) * DD + c];
#pragma unroll
    for (int r = 0; r < 8; ++r) {
      float4 xv = *(const float4*)(aggsrc + (size_t)(row0 + r) * DD + 4 * kk);
      acc[r] = fmaf(xv.x, w0, acc[r]);
      acc[r] = fmaf(xv.y, w1, acc[r]);
      acc[r] = fmaf(xv.z, w2, acc[r]);
      acc[r] = fmaf(xv.w, w3, acc[r]);
    }
  }
  float sc = lns[l * DD + c], bc = lnb[l * DD + c];
#pragma unroll
  for (int r = 0; r < 8; ++r) {
    float v = acc[r];
    float s = v;
    for (int m = 1; m < 64; m <<= 1) s += __shfl_xor(s, m);
    float mean = s * (1.f / 64.f);
    float cv = v - mean;
    float vv = cv * cv;
    for (int m = 1; m < 64; m <<= 1) vv += __shfl_xor(vv, m);
    vv *= (1.f / 64.f);
    float y = cv * __frsqrt_rn(vv + LN_EPS) * sc + bc;
    y = fmaxf(y, 0.f);
    float xo;
    if (init0)
      xo = (n0 + r == h0b) ? ws[OFF_QUERY + b * DD + c] : 0.f;
    else
      xo = xsrc[(size_t)(row0 + r) * DD + c];
    xdst[(size_t)(row0 + r) * DD + c] = xo + y;
  }
}

// ---------------- gather tail features into tokens (+pe) ----------------
__global__ void k_gather(const float* __restrict__ pe, const float* __restrict__ xfin,
                         float* __restrict__ ws, int w) {
  int i = blockIdx.x * 256 + threadIdx.x;
  if (i >= NB * NNEG * DD) return;
  int bj = i / DD, d = i % DD;
  int b = bj / NNEG;
  int t = ((const int*)ws)[OFF_TSW + bj];
  ws[OFF_TOK + bj * NW * DD + w * DD + d] = xfin[(b * NN + t) * DD + d] + pe[w * DD + d];
}

// ---------------- transformer + final MLP: LDS-staged weights, 4 rows/block ----------------
__global__ __launch_bounds__(768) void k_xform(
    const float* __restrict__ wq, const float* __restrict__ wk,
    const float* __restrict__ wv, const float* __restrict__ wo,
    const float* __restrict__ ffw1, const float* __restrict__ ffb1,
    const float* __restrict__ ffw2, const float* __restrict__ ffb2,
    const float* __restrict__ fln1s, const float* __restrict__ fln1b,
    const float* __restrict__ fln2s, const float* __restrict__ fln2b,
    const float* __restrict__ m1w, const float* __restrict__ m1b,
    const float* __restrict__ m2w, const float* __restrict__ m2b,
    float* __restrict__ ws, float* __restrict__ out) {
  __shared__ float tok[RPB][NW][DD], kvb[RPB][NW][DD], vvb[RPB][NW][DD];
  __shared__ float hbuf[RPB][NW][NFFN];
  __shared__ float feat[RPB][2 * DD];
  __shared__ float red[RPB][2];
  __shared__ float4 wbuf4[4352];  // 68 KB staging buffer (padded rows, 16B aligned)
  float* wbuf = (float*)wbuf4;
  (void)wbuf;
  int tid = threadIdx.x;
  int rr = tid / 192;
  int t192 = tid - rr * 192;
  int tk = t192 >> 6, d = t192 & 63;
  int row = blockIdx.x * RPB + rr, b = row / NNEG;
  tok[rr][tk][d] = ws[OFF_TOK + row * NW * DD + tk * DD + d];
  for (int f = 0; f < NFL; ++f) {
    // ---- stage wq,wk,wv,wo as 4x [64][68] (float4 rows of 17) ----
    {
      const float4* s0 = (const float4*)(wq + (size_t)f * DD * DD);
      const float4* s1 = (const float4*)(wk + (size_t)f * DD * DD);
      const float4* s2 = (const float4*)(wv + (size_t)f * DD * DD);
      const float4* s3 = (const float4*)(wo + (size_t)f * DD * DD);
      for (int idx = tid; idx < 4096; idx += 768) {
        int m = idx >> 10, rem = idx & 1023;
        int rrow = rem >> 4, c4 = rem & 15;
        const float4* s = (m == 0) ? s0 : (m == 1) ? s1 : (m == 2) ? s2 : s3;
        wbuf4[(m * 64 + rrow) * 17 + c4] = s[rem];
      }
    }
    __syncthreads();
    // ---- QKV from LDS ----
    float qd = 0.f, kd = 0.f, vd = 0.f;
#pragma unroll
    for (int kk = 0; kk < 16; ++kk) {
      float4 tv = *(const float4*)&tok[rr][tk][4 * kk];
      float4 aq = wbuf4[(0 * 64 + d) * 17 + kk];
      float4 ak = wbuf4[(1 * 64 + d) * 17 + kk];
      float4 av = wbuf4[(2 * 64 + d) * 17 + kk];
      qd += tv.x * aq.x + tv.y * aq.y + tv.z * aq.z + tv.w * aq.w;
      kd += tv.x * ak.x + tv.y * ak.y + tv.z * ak.z + tv.w * ak.w;
      vd += tv.x * av.x + tv.y * av.y + tv.z * av.z + tv.w * av.w;
    }
    kvb[rr][tk][d] = kd;
    vvb[rr][tk][d] = vd;
    __syncthreads();
    // ---- attention (head = d>>4) ----
    float sc[NW];
#pragma unroll
    for (int j = 0; j < NW; ++j) {
      float p = qd * kvb[rr][j][d];
      p += __shfl_xor(p, 1);
      p += __shfl_xor(p, 2);
      p += __shfl_xor(p, 4);
      p += __shfl_xor(p, 8);
      sc[j] = p * 0.25f;  // 1/sqrt(16)
    }
    float mx = fmaxf(sc[0], fmaxf(sc[1], sc[2]));
    float e0 = expf(sc[0] - mx), e1 = expf(sc[1] - mx), e2 = expf(sc[2] - mx);
    float inv = 1.f / (e0 + e1 + e2);
    float od = (e0 * vvb[rr][0][d] + e1 * vvb[rr][1][d] + e2 * vvb[rr][2][d]) * inv;
    __syncthreads();  // all reads of kvb/vvb done
    kvb[rr][tk][d] = od;  // wave-private from here
    // ---- o @ wo.T from LDS ----
    float ao = 0.f;
#pragma unroll
    for (int kk = 0; kk < 16; ++kk) {
      float4 ov = *(const float4*)&kvb[rr][tk][4 * kk];
      float4 w4 = wbuf4[(3 * 64 + d) * 17 + kk];
      ao += ov.x * w4.x + ov.y * w4.y + ov.z * w4.z + ov.w * w4.w;
    }
    float t1 = tok[rr][tk][d] + ao;
    // ---- LN1 ----
    float s = t1;
    for (int m = 1; m < 64; m <<= 1) s += __shfl_xor(s, m);
    float mean = s * (1.f / 64.f);
    float cv = t1 - mean;
    float v = cv * cv;
    for (int m = 1; m < 64; m <<= 1) v += __shfl_xor(v, m);
    v *= (1.f / 64.f);
    t1 = cv * __frsqrt_rn(v + LN_EPS) * fln1s[f * DD + d] + fln1b[f * DD + d];
    tok[rr][tk][d] = t1;
    __syncthreads();  // done with QKV/WO weights
    // ---- stage ffw1 as [256][68] ----
    {
      const float4* s4 = (const float4*)(ffw1 + (size_t)f * NFFN * DD);
      for (int idx = tid; idx < 4096; idx += 768) {
        int rrow = idx >> 4, c4 = idx & 15;
        wbuf4[rrow * 17 + c4] = s4[idx];
      }
    }
    __syncthreads();
    // ---- FFN1: 4 hidden units per thread ----
    float h[4];
#pragma unroll
    for (int uu = 0; uu < 4; ++uu) h[uu] = ffb1[f * NFFN + d + 64 * uu];
#pragma unroll
    for (int kk = 0; kk < 16; ++kk) {
      float4 tv = *(const float4*)&tok[rr][tk][4 * kk];
      float4 w0 = wbuf4[(d + 0) * 17 + kk];
      float4 w1 = wbuf4[(d + 64) * 17 + kk];
      float4 w2 = wbuf4[(d + 128) * 17 + kk];
      float4 w3 = wbuf4[(d + 192) * 17 + kk];
      h[0] += tv.x * w0.x + tv.y * w0.y + tv.z * w0.z + tv.w * w0.w;
      h[1] += tv.x * w1.x + tv.y * w1.y + tv.z * w1.z + tv.w * w1.w;
      h[2] += tv.x * w2.x + tv.y * w2.y + tv.z * w2.z + tv.w * w2.w;
      h[3] += tv.x * w3.x + tv.y * w3.y + tv.z * w3.z + tv.w * w3.w;
    }
#pragma unroll
    for (int uu = 0; uu < 4; ++uu) hbuf[rr][tk][d + 64 * uu] = fmaxf(h[uu], 0.f);
    __syncthreads();  // done with ffw1 weights
    // ---- stage ffw2 as [64][260] (float4 rows of 65) ----
    {
      const float4* s4 = (const float4*)(ffw2 + (size_t)f * DD * NFFN);
      for (int idx = tid; idx < 4096; idx += 768) {
        int rrow = idx >> 6, c4 = idx & 63;
        wbuf4[rrow * 65 + c4] = s4[idx];
      }
    }
    __syncthreads();
    // ---- FFN2 ----
    float ff = ffb2[f * DD + d];
#pragma unroll 8
    for (int kk = 0; kk < 64; ++kk) {
      float4 hv = *(const float4*)&hbuf[rr][tk][4 * kk];
      float4 w4 = wbuf4[d * 65 + kk];
      ff += hv.x * w4.x + hv.y * w4.y + hv.z * w4.z + hv.w * w4.w;
    }
    float t2 = t1 + ff;
    // ---- LN2 ----
    s = t2;
    for (int m = 1; m < 64; m <<= 1) s += __shfl_xor(s, m);
    mean = s * (1.f / 64.f);
    cv = t2 - mean;
    v = cv * cv;
    for (int m = 1; m < 64; m <<= 1) v += __shfl_xor(v, m);
    v *= (1.f / 64.f);
    t2 = cv * __frsqrt_rn(v + LN_EPS) * fln2s[f * DD + d] + fln2b[f * DD + d];
    tok[rr][tk][d] = t2;
    __syncthreads();  // wbuf free for next phase
  }
  // ---- final MLP: stage m1 [128][132] while writing feat ----
  if (tk == 2) {
    feat[rr][d] = tok[rr][2][d];
    feat[rr][DD + d] = ws[OFF_QUERY + b * DD + d];
  }
  {
    const float4* s4 = (const float4*)m1w;
    for (int idx = tid; idx < 4096; idx += 768) {
      int rrow = idx >> 5, c4 = idx & 31;
      wbuf4[rrow * 33 + c4] = s4[idx];
    }
  }
  __syncthreads();
  float partial = 0.f;
  if (t192 < 2 * DD) {
    int hh = t192;
    float acc = m1b[hh];
#pragma unroll
    for (int kk = 0; kk < 32; ++kk) {
      float4 fv = *(const float4*)&feat[rr][4 * kk];
      float4 w4 = wbuf4[hh * 33 + kk];
      acc += fv.x * w4.x + fv.y * w4.y + fv.z * w4.z + fv.w * w4.w;
    }
    acc = fmaxf(acc, 0.f);
    partial = acc * m2w[hh];
  }
  for (int m = 1; m < 64; m <<= 1) partial += __shfl_xor(partial, m);
  if (d == 0 && tk < 2) red[rr][tk] = partial;
  __syncthreads();
  if (t192 == 0) out[row] = red[rr][0] + red[rr][1] + m2b[0];
}

extern "C" void kernel_launch(void* const* d_in, const int* in_sizes, int n_in,
                              void* d_out, int out_size, void* d_ws, size_t ws_size,
                              hipStream_t stream) {
  const int* qt = (const int*)d_in[0];
  const int* eidx = (const int*)d_in[1];
  const int* etype = (const int*)d_in[2];
  const int* etime = (const int*)d_in[3];
  const float* qemb = (const float*)d_in[4];
  const float* ew = (const float*)d_in[5];
  const float* rlw = (const float*)d_in[6];
  const float* rlb = (const float*)d_in[7];
  const float* tw = (const float*)d_in[8];
  const float* tb = (const float*)d_in[9];
  const float* linw = (const float*)d_in[10];
  const float* linb = (const float*)d_in[11];
  const float* lns = (const float*)d_in[12];
  const float* lnb = (const float*)d_in[13];
  const float* pe = (const float*)d_in[14];
  const float* wq = (const float*)d_in[15];
  const float* wk = (const float*)d_in[16];
  const float* wv = (const float*)d_in[17];
  const float* wo = (const float*)d_in[18];
  const float* ffw1 = (const float*)d_in[19];
  const float* ffb1 = (const float*)d_in[20];
  const float* ffw2 = (const float*)d_in[21];
  const float* ffb2 = (const float*)d_in[22];
  const float* fln1s = (const float*)d_in[23];
  const float* fln1b = (const float*)d_in[24];
  const float* fln2s = (const float*)d_in[25];
  const float* fln2b = (const float*)d_in[26];
  const float* m1w = (const float*)d_in[27];
  const float* m1b = (const float*)d_in[28];
  const float* m2w = (const float*)d_in[29];
  const float* m2b = (const float*)d_in[30];
  float* ws = (float*)d_ws;
  float* out = (float*)d_out;

  k_prep<<<1, 256, 0, stream>>>(qt, qemb, ws);
  k_mint<<<(NE + 255) / 256, 256, 0, stream>>>(etime, ws);
  k_zero_ptr<<<(NW * (NN + 1) + 255) / 256, 256, 0, stream>>>(ws);
  k_transpose<<<(NL * 2 * DD * DD + 255) / 256, 256, 0, stream>>>(linw, ws);
  k_rel<<<dim3(NR * DD / 256, NL), 256, 0, stream>>>(rlw, rlb, ws);
  k_hist<<<dim3((NE + 255) / 256, NW), 256, 0, stream>>>(eidx, ws);
  k_scan<<<NW, 256, 0, stream>>>(ws);
  k_curinit<<<(NW * NN + 255) / 256, 256, 0, stream>>>(ws);
  k_scatter<<<dim3((NE + 255) / 256, NW), 256, 0, stream>>>(eidx, etype, etime, ew, ws);

  float* X = ws + OFF_X;
  float* X2 = ws + OFF_X2;
  for (int w = 0; w < NW; ++w) {
    float* cur = X;
    float* nxt = X2;
    for (int l = 0; l < NL; ++l) {
      int init0 = (l == 0) ? 1 : 0;
      k_agg<<<NN / 4, 256, 0, stream>>>(tw, tb, cur, ws, w, l, init0);
      k_gemm<<<NB * NN / 32, 256, 0, stream>>>(linb, lns, lnb, cur, nxt, ws, l, init0);
      float* t = cur; cur = nxt; nxt = t;
    }
    k_gather<<<(NB * NNEG * DD + 255) / 256, 256, 0, stream>>>(pe, cur, ws, w);
  }
  k_xform<<<NB * NNEG / RPB, 768, 0, stream>>>(wq, wk, wv, wo, ffw1, ffb1, ffw2, ffb2,
                                                fln1s, fln1b, fln2s, fln2b, m1w, m1b, m2w,
                                                m2b, ws, out);
}